// Round 1
// baseline (1021.448 us; speedup 1.0000x reference)
//
#include <hip/hip_runtime.h>
#include <math.h>

// Problem constants (reference: EMBED_DIM=256, NUM_HEADS=4, HEAD_DIM=64, B=4, N0=N1=2048)
#define BATCH 4
#define SEQ 2048
#define DMODEL 256
#define NH 4
#define HD 64
#define MROWS (BATCH * SEQ)  // 8192 rows for all row-major GEMMs

// ---------------------------------------------------------------------------
// Generic tiled fp32 GEMM: C[M,N] = epilogue(A[M,K] @ W[K,N] + bias[N])
//   MODE 0: C = A@W + bias
//   MODE 1: A is concat(A[:, :256], A2[:, :256]) along K (both lda=256)
//   MODE 2: C = resid + A@W + bias   (resid has ld = N)
// Tile: BM=BN=64, BK=16; 256 threads; 4x4 micro-tile per thread.
// ---------------------------------------------------------------------------
template <int MODE>
__global__ __launch_bounds__(256) void gemm_k(
    const float* __restrict__ A, const float* __restrict__ A2,
    const float* __restrict__ W, const float* __restrict__ bias,
    const float* __restrict__ resid, float* __restrict__ C,
    int M, int N, int K) {
  __shared__ float As[16][64];  // [k][row]  (A transposed into LDS)
  __shared__ float Ws[16][64];  // [k][col]  (natural)

  const int t = threadIdx.x;
  const int row0 = blockIdx.x * 64;
  const int col0 = blockIdx.y * 64;
  const int rg = t >> 4;          // 0..15 row group (4 rows each)
  const int cg = t & 15;          // 0..15 col group (4 cols each)
  const int lr = t >> 2;          // 0..63 A-load row
  const int lc4 = (t & 3) << 2;   // 0,4,8,12 A-load k-offset
  const int wr = t >> 4;          // 0..15 W-load k-row
  const int wc4 = (t & 15) << 2;  // W-load col offset

  float acc[4][4] = {};

  for (int k0 = 0; k0 < K; k0 += 16) {
    const float* Ap;
    int lda, kk;
    if (MODE == 1) {
      if (k0 < DMODEL) { Ap = A;  lda = DMODEL; kk = k0; }
      else             { Ap = A2; lda = DMODEL; kk = k0 - DMODEL; }
    } else {
      Ap = A; lda = K; kk = k0;
    }
    float4 av = *(const float4*)&Ap[(size_t)(row0 + lr) * lda + kk + lc4];
    float4 wv = *(const float4*)&W[(size_t)(k0 + wr) * N + col0 + wc4];

    __syncthreads();  // previous tile's LDS reads complete
    As[lc4 + 0][lr] = av.x;
    As[lc4 + 1][lr] = av.y;
    As[lc4 + 2][lr] = av.z;
    As[lc4 + 3][lr] = av.w;
    *(float4*)&Ws[wr][wc4] = wv;
    __syncthreads();

#pragma unroll
    for (int j = 0; j < 16; ++j) {
      float4 a = *(const float4*)&As[j][rg << 2];
      float4 w = *(const float4*)&Ws[j][cg << 2];
      float af[4] = {a.x, a.y, a.z, a.w};
      float wf[4] = {w.x, w.y, w.z, w.w};
#pragma unroll
      for (int ii = 0; ii < 4; ++ii)
#pragma unroll
        for (int jj = 0; jj < 4; ++jj) acc[ii][jj] += af[ii] * wf[jj];
    }
  }

#pragma unroll
  for (int i = 0; i < 4; ++i) {
    int r = row0 + (rg << 2) + i;
    int c = col0 + (cg << 2);
    float4 bv = *(const float4*)&bias[c];
    float4 o;
    o.x = acc[i][0] + bv.x;
    o.y = acc[i][1] + bv.y;
    o.z = acc[i][2] + bv.z;
    o.w = acc[i][3] + bv.w;
    if (MODE == 2) {
      float4 rv = *(const float4*)&resid[(size_t)r * N + c];
      o.x += rv.x; o.y += rv.y; o.z += rv.z; o.w += rv.w;
    }
    *(float4*)&C[(size_t)r * N + c] = o;
  }
}

// ---------------------------------------------------------------------------
// Flash-style cross attention, one (b, h, q-tile of 64) per block, fp32.
// Q,K,V,O all [B, SEQ, DMODEL] with head h occupying cols h*64..h*64+63.
// Online softmax; S never materialized in global memory.
// ---------------------------------------------------------------------------
__global__ __launch_bounds__(256) void flash_k(
    const float* __restrict__ Q, const float* __restrict__ Kb,
    const float* __restrict__ Vb, float* __restrict__ O) {
  __shared__ float Qs[64][64];  // [dim][qrow]   (transposed)
  __shared__ float Ks[64][64];  // [dim][kvcol]  (transposed)
  __shared__ float Vs[64][64];  // [kvrow][dim]  (natural)
  __shared__ float Ps[64][64];  // [kvrow][qrow] (transposed P)

  const int t = threadIdx.x;
  const int qt = blockIdx.x, h = blockIdx.y, b = blockIdx.z;
  const int rg = t >> 4;  // 0..15, handles q-rows rg*4..rg*4+3
  const int cg = t & 15;  // 0..15, handles 4 kv-cols (QK) / 4 dim-cols (PV)
  const size_t qbase = (size_t)b * SEQ + (size_t)qt * 64;
  const int hoff = h * HD;
  const float scale = 0.125f;  // 1/sqrt(64)

  // Load Q tile transposed
  for (int i = t; i < 64 * 16; i += 256) {
    int r = i >> 4, j4 = (i & 15) << 2;
    float4 v = *(const float4*)&Q[(qbase + r) * DMODEL + hoff + j4];
    Qs[j4 + 0][r] = v.x; Qs[j4 + 1][r] = v.y;
    Qs[j4 + 2][r] = v.z; Qs[j4 + 3][r] = v.w;
  }

  float m_r[4], l_r[4], Oacc[4][4] = {};
#pragma unroll
  for (int i = 0; i < 4; ++i) { m_r[i] = -1e30f; l_r[i] = 0.f; }

  for (int kt = 0; kt < SEQ / 64; ++kt) {
    __syncthreads();  // previous iteration's Ps/Vs reads complete
    const size_t kbase = (size_t)b * SEQ + (size_t)kt * 64;
    for (int i = t; i < 64 * 16; i += 256) {
      int r = i >> 4, j4 = (i & 15) << 2;
      float4 kv = *(const float4*)&Kb[(kbase + r) * DMODEL + hoff + j4];
      Ks[j4 + 0][r] = kv.x; Ks[j4 + 1][r] = kv.y;
      Ks[j4 + 2][r] = kv.z; Ks[j4 + 3][r] = kv.w;
      float4 vv = *(const float4*)&Vb[(kbase + r) * DMODEL + hoff + j4];
      *(float4*)&Vs[r][j4] = vv;
    }
    __syncthreads();

    // S = Q @ K^T  (4x4 per thread)
    float s[4][4] = {};
#pragma unroll 8
    for (int j = 0; j < 64; ++j) {
      float4 qv = *(const float4*)&Qs[j][rg << 2];
      float4 kv = *(const float4*)&Ks[j][cg << 2];
      float qf[4] = {qv.x, qv.y, qv.z, qv.w};
      float kf[4] = {kv.x, kv.y, kv.z, kv.w};
#pragma unroll
      for (int ii = 0; ii < 4; ++ii)
#pragma unroll
        for (int jj = 0; jj < 4; ++jj) s[ii][jj] += qf[ii] * kf[jj];
    }

    // Online softmax per q-row; row is shared by the 16 lanes with equal rg
    // (contiguous 16-lane groups within a wave -> shfl_xor width 16).
#pragma unroll
    for (int i = 0; i < 4; ++i) {
#pragma unroll
      for (int jj = 0; jj < 4; ++jj) s[i][jj] *= scale;
      float tm = fmaxf(fmaxf(s[i][0], s[i][1]), fmaxf(s[i][2], s[i][3]));
      tm = fmaxf(tm, __shfl_xor(tm, 1, 16));
      tm = fmaxf(tm, __shfl_xor(tm, 2, 16));
      tm = fmaxf(tm, __shfl_xor(tm, 4, 16));
      tm = fmaxf(tm, __shfl_xor(tm, 8, 16));
      float mnew = fmaxf(m_r[i], tm);
      float alpha = __expf(m_r[i] - mnew);
      float rsum = 0.f;
#pragma unroll
      for (int jj = 0; jj < 4; ++jj) {
        s[i][jj] = __expf(s[i][jj] - mnew);
        rsum += s[i][jj];
      }
      rsum += __shfl_xor(rsum, 1, 16);
      rsum += __shfl_xor(rsum, 2, 16);
      rsum += __shfl_xor(rsum, 4, 16);
      rsum += __shfl_xor(rsum, 8, 16);
      m_r[i] = mnew;
      l_r[i] = l_r[i] * alpha + rsum;
#pragma unroll
      for (int jj = 0; jj < 4; ++jj) {
        Oacc[i][jj] *= alpha;
        Ps[(cg << 2) + jj][(rg << 2) + i] = s[i][jj];
      }
    }
    __syncthreads();  // Ps visible

    // O += P @ V  (4 q-rows x 4 dim-cols per thread)
#pragma unroll 8
    for (int j = 0; j < 64; ++j) {
      float4 pv = *(const float4*)&Ps[j][rg << 2];
      float4 vv = *(const float4*)&Vs[j][cg << 2];
      float pf[4] = {pv.x, pv.y, pv.z, pv.w};
      float vf[4] = {vv.x, vv.y, vv.z, vv.w};
#pragma unroll
      for (int ii = 0; ii < 4; ++ii)
#pragma unroll
        for (int jj = 0; jj < 4; ++jj) Oacc[ii][jj] += pf[ii] * vf[jj];
    }
  }

#pragma unroll
  for (int i = 0; i < 4; ++i) {
    float inv = 1.0f / l_r[i];
    float4 o = {Oacc[i][0] * inv, Oacc[i][1] * inv,
                Oacc[i][2] * inv, Oacc[i][3] * inv};
    *(float4*)&O[(qbase + (rg << 2) + i) * DMODEL + hoff + (cg << 2)] = o;
  }
}

// ---------------------------------------------------------------------------
// In-place LayerNorm (over 512) + exact GELU; one block per row of 512.
// ---------------------------------------------------------------------------
__global__ __launch_bounds__(256) void ln_gelu_k(
    float* __restrict__ Y, const float* __restrict__ sc,
    const float* __restrict__ bi) {
  const int t = threadIdx.x;
  float* p = Y + (size_t)blockIdx.x * 512;
  float v0 = p[t], v1 = p[t + 256];
  float s1 = v0 + v1, s2 = v0 * v0 + v1 * v1;
#pragma unroll
  for (int m = 1; m < 64; m <<= 1) {
    s1 += __shfl_xor(s1, m);
    s2 += __shfl_xor(s2, m);
  }
  __shared__ float red[8];
  int w = t >> 6;
  if ((t & 63) == 0) { red[w] = s1; red[4 + w] = s2; }
  __syncthreads();
  s1 = red[0] + red[1] + red[2] + red[3];
  s2 = red[4] + red[5] + red[6] + red[7];
  float mu = s1 * (1.0f / 512.0f);
  float var = s2 * (1.0f / 512.0f) - mu * mu;
  float rstd = rsqrtf(var + 1e-5f);
  float y0 = (v0 - mu) * rstd * sc[t] + bi[t];
  float y1 = (v1 - mu) * rstd * sc[t + 256] + bi[t + 256];
  y0 = 0.5f * y0 * (1.0f + erff(y0 * 0.70710678118654752f));
  y1 = 0.5f * y1 * (1.0f + erff(y1 * 0.70710678118654752f));
  p[t] = y0;
  p[t + 256] = y1;
}

// ---------------------------------------------------------------------------
// Launch. Workspace layout (fp32, 12 * 2M floats = 48 MB), with stream-order-
// safe aliasing:
//   [0..2M)   qk0  -> later mp0 (m0 @ Wout)
//   [2M..4M)  qk1  -> later mp1
//   [4M..8M)  v0,v1 -> later y0 (8192 x 512)
//   [8M..12M) m0,m1 -> later y1 (8192 x 512)
// ---------------------------------------------------------------------------
extern "C" void kernel_launch(void* const* d_in, const int* in_sizes, int n_in,
                              void* d_out, int out_size, void* d_ws,
                              size_t ws_size, hipStream_t stream) {
  const float* x0   = (const float*)d_in[0];
  const float* x1   = (const float*)d_in[1];
  const float* Wqk  = (const float*)d_in[2];
  const float* bqk  = (const float*)d_in[3];
  const float* Wv   = (const float*)d_in[4];
  const float* bv   = (const float*)d_in[5];
  const float* Wout = (const float*)d_in[6];
  const float* bout = (const float*)d_in[7];
  const float* W0   = (const float*)d_in[8];
  const float* b0   = (const float*)d_in[9];
  const float* lns  = (const float*)d_in[10];
  const float* lnb  = (const float*)d_in[11];
  const float* W3   = (const float*)d_in[12];
  const float* b3   = (const float*)d_in[13];

  float* ws = (float*)d_ws;
  const size_t SZ = (size_t)MROWS * DMODEL;  // 2M floats
  float* qk0 = ws;
  float* qk1 = ws + SZ;
  float* v0  = ws + 2 * SZ;
  float* v1  = ws + 3 * SZ;
  float* m0  = ws + 4 * SZ;
  float* m1  = ws + 5 * SZ;
  float* mp0 = qk0;  // reuse after both attention passes
  float* mp1 = qk1;
  float* y0  = v0;   // spans v0+v1 (8192 x 512)
  float* y1  = m0;   // spans m0+m1 (8192 x 512)
  float* out0 = (float*)d_out;
  float* out1 = out0 + SZ;

  dim3 blk(256);
  dim3 g256(MROWS / 64, DMODEL / 64);  // (128, 4)
  dim3 g512(MROWS / 64, 512 / 64);     // (128, 8)
  dim3 ga(SEQ / 64, NH, BATCH);        // (32, 4, 4)

  // QK / V projections (shared Wqk for both streams)
  gemm_k<0><<<g256, blk, 0, stream>>>(x0, nullptr, Wqk, bqk, nullptr, qk0, MROWS, DMODEL, DMODEL);
  gemm_k<0><<<g256, blk, 0, stream>>>(x1, nullptr, Wqk, bqk, nullptr, qk1, MROWS, DMODEL, DMODEL);
  gemm_k<0><<<g256, blk, 0, stream>>>(x0, nullptr, Wv, bv, nullptr, v0, MROWS, DMODEL, DMODEL);
  gemm_k<0><<<g256, blk, 0, stream>>>(x1, nullptr, Wv, bv, nullptr, v1, MROWS, DMODEL, DMODEL);

  // Bidirectional cross attention: m0 = Attn(qk0, qk1, v1); m1 = Attn(qk1, qk0, v0)
  flash_k<<<ga, blk, 0, stream>>>(qk0, qk1, v1, m0);
  flash_k<<<ga, blk, 0, stream>>>(qk1, qk0, v0, m1);

  // Output projections (overwrite qk buffers — attention done)
  gemm_k<0><<<g256, blk, 0, stream>>>(m0, nullptr, Wout, bout, nullptr, mp0, MROWS, DMODEL, DMODEL);
  gemm_k<0><<<g256, blk, 0, stream>>>(m1, nullptr, Wout, bout, nullptr, mp1, MROWS, DMODEL, DMODEL);

  // FFN1: y = concat(x, mproj) @ W0 + b0
  gemm_k<1><<<g512, blk, 0, stream>>>(x0, mp0, W0, b0, nullptr, y0, MROWS, 512, 512);
  gemm_k<1><<<g512, blk, 0, stream>>>(x1, mp1, W0, b0, nullptr, y1, MROWS, 512, 512);

  // LayerNorm + exact GELU, in place
  ln_gelu_k<<<dim3(MROWS), blk, 0, stream>>>(y0, lns, lnb);
  ln_gelu_k<<<dim3(MROWS), blk, 0, stream>>>(y1, lns, lnb);

  // FFN2: out = x + y @ W3 + b3
  gemm_k<2><<<g256, blk, 0, stream>>>(y0, nullptr, W3, b3, x0, out0, MROWS, DMODEL, 512);
  gemm_k<2><<<g256, blk, 0, stream>>>(y1, nullptr, W3, b3, x1, out1, MROWS, DMODEL, 512);
}

// Round 2
// 590.985 us; speedup vs baseline: 1.7284x; 1.7284x over previous
//
#include <hip/hip_runtime.h>
#include <math.h>

// Problem constants (reference: EMBED_DIM=256, NUM_HEADS=4, HEAD_DIM=64, B=4, N0=N1=2048)
#define BATCH 4
#define SEQ 2048
#define DMODEL 256
#define NH 4
#define HD 64
#define MROWS (BATCH * SEQ)  // 8192

typedef short bf16x8 __attribute__((ext_vector_type(8)));
typedef float f32x4 __attribute__((ext_vector_type(4)));

__device__ __forceinline__ unsigned short f2bf(float x) {
  union { float f; unsigned int u; } v;
  v.f = x;
  unsigned int r = (v.u + 0x7FFF + ((v.u >> 16) & 1)) >> 16;
  return (unsigned short)r;
}

// ---------------------------------------------------------------------------
// Tiled fp32 GEMM: C[M,N] = epilogue(A[M,K] @ W[K,N] + bias[N])
//   MODE 0: fp32 C = A@W + bias
//   MODE 1: A = concat(A, A2) along K (both lda=256), fp32 out
//   MODE 2: fp32 C = resid + A@W + bias
//   MODE 3: bf16 C (natural [M][N] layout)            -> qk projections
//   MODE 4: bf16 C transposed per head: [B][H][HD][SEQ] -> v projections
// Tile BM=BN=64, BK=16; 256 threads; 4x4 micro-tile.
// ---------------------------------------------------------------------------
template <int MODE>
__global__ __launch_bounds__(256) void gemm_k(
    const float* __restrict__ A, const float* __restrict__ A2,
    const float* __restrict__ W, const float* __restrict__ bias,
    const float* __restrict__ resid, void* __restrict__ Cv,
    int M, int N, int K) {
  __shared__ float As[16][64];  // [k][row]
  __shared__ float Ws[16][64];  // [k][col]

  const int t = threadIdx.x;
  const int row0 = blockIdx.x * 64;
  const int col0 = blockIdx.y * 64;
  const int rg = t >> 4;
  const int cg = t & 15;
  const int lr = t >> 2;
  const int lc4 = (t & 3) << 2;
  const int wr = t >> 4;
  const int wc4 = (t & 15) << 2;

  float acc[4][4] = {};

  for (int k0 = 0; k0 < K; k0 += 16) {
    const float* Ap;
    int lda, kk;
    if (MODE == 1) {
      if (k0 < DMODEL) { Ap = A;  lda = DMODEL; kk = k0; }
      else             { Ap = A2; lda = DMODEL; kk = k0 - DMODEL; }
    } else {
      Ap = A; lda = K; kk = k0;
    }
    float4 av = *(const float4*)&Ap[(size_t)(row0 + lr) * lda + kk + lc4];
    float4 wv = *(const float4*)&W[(size_t)(k0 + wr) * N + col0 + wc4];

    __syncthreads();
    As[lc4 + 0][lr] = av.x;
    As[lc4 + 1][lr] = av.y;
    As[lc4 + 2][lr] = av.z;
    As[lc4 + 3][lr] = av.w;
    *(float4*)&Ws[wr][wc4] = wv;
    __syncthreads();

#pragma unroll
    for (int j = 0; j < 16; ++j) {
      float4 a = *(const float4*)&As[j][rg << 2];
      float4 w = *(const float4*)&Ws[j][cg << 2];
      float af[4] = {a.x, a.y, a.z, a.w};
      float wf[4] = {w.x, w.y, w.z, w.w};
#pragma unroll
      for (int ii = 0; ii < 4; ++ii)
#pragma unroll
        for (int jj = 0; jj < 4; ++jj) acc[ii][jj] += af[ii] * wf[jj];
    }
  }

  const int r0 = row0 + (rg << 2);
  const int c0 = col0 + (cg << 2);

  if (MODE == 4) {
    // bf16 transposed-head write: Vt[((b*NH+h)*HD+hd)*SEQ + n]
    unsigned short* Cb = (unsigned short*)Cv;
    int b_ = r0 >> 11;       // row0 tiles never cross a 2048-row batch segment
    int n0 = r0 & 2047;
#pragma unroll
    for (int cc = 0; cc < 4; ++cc) {
      int col = c0 + cc;
      int hh = col >> 6, hd = col & 63;
      float bb = bias[col];
      ushort4 o;
      o.x = f2bf(acc[0][cc] + bb);
      o.y = f2bf(acc[1][cc] + bb);
      o.z = f2bf(acc[2][cc] + bb);
      o.w = f2bf(acc[3][cc] + bb);
      *(ushort4*)&Cb[((size_t)(b_ * NH + hh) * HD + hd) * SEQ + n0] = o;
    }
    return;
  }

#pragma unroll
  for (int i = 0; i < 4; ++i) {
    int r = r0 + i;
    float4 bv = *(const float4*)&bias[c0];
    float4 o;
    o.x = acc[i][0] + bv.x;
    o.y = acc[i][1] + bv.y;
    o.z = acc[i][2] + bv.z;
    o.w = acc[i][3] + bv.w;
    if (MODE == 2) {
      float4 rv = *(const float4*)&resid[(size_t)r * N + c0];
      o.x += rv.x; o.y += rv.y; o.z += rv.z; o.w += rv.w;
    }
    if (MODE == 3) {
      unsigned short* Cb = (unsigned short*)Cv;
      ushort4 ob = {f2bf(o.x), f2bf(o.y), f2bf(o.z), f2bf(o.w)};
      *(ushort4*)&Cb[(size_t)r * N + c0] = ob;
    } else {
      float* C = (float*)Cv;
      *(float4*)&C[(size_t)r * N + c0] = o;
    }
  }
}

// ---------------------------------------------------------------------------
// MFMA bf16 flash cross-attention. One (b, h, 64-row q-tile) per block,
// 4 waves; wave w owns q-band w*16..w*16+15. mfma_f32_16x16x32_bf16.
// Verified fragment layouts: A: m=lane&15, k=quad*8+j; B: n=lane&15,
// k=quad*8+j; C/D: col=lane&15, row=quad*4+reg.
// LDS staged in lane-linear 16B slots -> conflict-free ds_read_b128.
// Q: [8192][256] bf16 natural; K same; Vt: [B][H][HD][SEQ] bf16; O fp32.
// ---------------------------------------------------------------------------
__global__ __launch_bounds__(256) void flash_mfma(
    const unsigned short* __restrict__ Qb, const unsigned short* __restrict__ Kb,
    const unsigned short* __restrict__ Vt, float* __restrict__ O) {
  __shared__ unsigned short Qs[4096];  // [w][s][qd][r16][8]  8 KB
  __shared__ unsigned short Ks[4096];  // [tk][s][qd][kv16][8]
  __shared__ unsigned short Vs[4096];  // [td][s'][qd][d16][8]
  __shared__ unsigned short Ps[4096];  // per-wave 1024: [s'][qd'][q16][8]

  const int t = threadIdx.x;
  const int w = t >> 6, lane = t & 63;
  const int l15 = lane & 15, qd = lane >> 4;
  const int qt = blockIdx.x, h = blockIdx.y, b = blockIdx.z;
  const size_t qrow0 = (size_t)b * SEQ + (size_t)qt * 64;
  const int hoff = h * HD;
  const unsigned short* vtb = Vt + (size_t)(b * NH + h) * HD * SEQ;

  // Stage Q (64 rows x 64 dims bf16 = 512 x 16B chunks)
  for (int c = t; c < 512; c += 256) {
    int r = c >> 3, kc = c & 7;
    uint4 d = *(const uint4*)&Qb[(qrow0 + r) * DMODEL + hoff + kc * 8];
    int slot = (((r >> 4) * 2 + (kc >> 2)) * 4 + (kc & 3)) * 16 + (r & 15);
    *(uint4*)&Qs[slot * 8] = d;
  }
  __syncthreads();

  bf16x8 aQ[2];
  aQ[0] = *(const bf16x8*)&Qs[((w * 2 + 0) * 64 + lane) * 8];
  aQ[1] = *(const bf16x8*)&Qs[((w * 2 + 1) * 64 + lane) * 8];

  const float sc2 = 0.125f * 1.44269504f;  // scale * log2(e)
  float m_r[4], l_r[4];
  f32x4 Oacc[4];
#pragma unroll
  for (int r = 0; r < 4; ++r) { m_r[r] = -1e30f; l_r[r] = 0.f; }
#pragma unroll
  for (int td = 0; td < 4; ++td) Oacc[td] = (f32x4){0.f, 0.f, 0.f, 0.f};

  for (int kt = 0; kt < SEQ / 64; ++kt) {
    __syncthreads();  // previous iteration's Ks/Vs reads complete
    const size_t krow0 = (size_t)b * SEQ + (size_t)kt * 64;
    for (int c = t; c < 512; c += 256) {
      int r = c >> 3, kc = c & 7;
      int slot = (((r >> 4) * 2 + (kc >> 2)) * 4 + (kc & 3)) * 16 + (r & 15);
      uint4 dk = *(const uint4*)&Kb[(krow0 + r) * DMODEL + hoff + kc * 8];
      *(uint4*)&Ks[slot * 8] = dk;
      uint4 dv = *(const uint4*)&vtb[(size_t)r * SEQ + kt * 64 + kc * 8];
      *(uint4*)&Vs[slot * 8] = dv;  // r==d row, kc==kv chunk: same slot math
    }
    __syncthreads();

    // S = Q @ K^T : 4 kv-tiles of 16, K-dim 64 = 2 MFMA steps
    f32x4 S[4];
#pragma unroll
    for (int tk = 0; tk < 4; ++tk) {
      bf16x8 b0 = *(const bf16x8*)&Ks[((tk * 2 + 0) * 64 + lane) * 8];
      bf16x8 b1 = *(const bf16x8*)&Ks[((tk * 2 + 1) * 64 + lane) * 8];
      f32x4 acc = {0.f, 0.f, 0.f, 0.f};
      acc = __builtin_amdgcn_mfma_f32_16x16x32_bf16(aQ[0], b0, acc, 0, 0, 0);
      acc = __builtin_amdgcn_mfma_f32_16x16x32_bf16(aQ[1], b1, acc, 0, 0, 0);
      S[tk] = acc;
    }

    // Online softmax (base-2). Lane's reg r holds q-row qd*4+r, kv col
    // tk*16 + l15. Row reduction across the 16 consecutive lanes of a quad.
    float p[4][4];
    float alpha[4];
#pragma unroll
    for (int r = 0; r < 4; ++r) {
      float s0 = S[0][r] * sc2, s1 = S[1][r] * sc2;
      float s2 = S[2][r] * sc2, s3 = S[3][r] * sc2;
      float mx = fmaxf(fmaxf(s0, s1), fmaxf(s2, s3));
      mx = fmaxf(mx, __shfl_xor(mx, 1, 16));
      mx = fmaxf(mx, __shfl_xor(mx, 2, 16));
      mx = fmaxf(mx, __shfl_xor(mx, 4, 16));
      mx = fmaxf(mx, __shfl_xor(mx, 8, 16));
      float mnew = fmaxf(m_r[r], mx);
      float a = exp2f(m_r[r] - mnew);
      float p0 = exp2f(s0 - mnew), p1 = exp2f(s1 - mnew);
      float p2 = exp2f(s2 - mnew), p3 = exp2f(s3 - mnew);
      float rs = p0 + p1 + p2 + p3;
      rs += __shfl_xor(rs, 1, 16);
      rs += __shfl_xor(rs, 2, 16);
      rs += __shfl_xor(rs, 4, 16);
      rs += __shfl_xor(rs, 8, 16);
      m_r[r] = mnew;
      l_r[r] = l_r[r] * a + rs;
      alpha[r] = a;
      p[0][r] = p0; p[1][r] = p1; p[2][r] = p2; p[3][r] = p3;
    }
#pragma unroll
    for (int td = 0; td < 4; ++td)
#pragma unroll
      for (int r = 0; r < 4; ++r) Oacc[td][r] *= alpha[r];

    // P (C-layout) -> Ps in A-operand layout, bf16. Wave-private region;
    // LDS ops within a wave are processed in order, no barrier needed.
    {
      int j = l15 & 7;
      int hi = l15 >> 3;
#pragma unroll
      for (int tk = 0; tk < 4; ++tk) {
        int sP = tk >> 1;
        int qdP = (tk * 2 + hi) & 3;
        int base = w * 128 + (sP * 4 + qdP) * 16;
#pragma unroll
        for (int r = 0; r < 4; ++r) {
          Ps[(base + qd * 4 + r) * 8 + j] = f2bf(p[tk][r]);
        }
      }
    }
    bf16x8 aP0 = *(const bf16x8*)&Ps[(w * 128 + 0 * 64 + lane) * 8];
    bf16x8 aP1 = *(const bf16x8*)&Ps[(w * 128 + 1 * 64 + lane) * 8];

    // O += P @ V : 4 d-tiles, kv-dim 64 = 2 MFMA steps
#pragma unroll
    for (int td = 0; td < 4; ++td) {
      bf16x8 v0 = *(const bf16x8*)&Vs[((td * 2 + 0) * 64 + lane) * 8];
      bf16x8 v1 = *(const bf16x8*)&Vs[((td * 2 + 1) * 64 + lane) * 8];
      Oacc[td] = __builtin_amdgcn_mfma_f32_16x16x32_bf16(aP0, v0, Oacc[td], 0, 0, 0);
      Oacc[td] = __builtin_amdgcn_mfma_f32_16x16x32_bf16(aP1, v1, Oacc[td], 0, 0, 0);
    }
  }

  // Epilogue: divide by l, write fp32 O (C-layout scatter, 4x16 rowsx cols)
#pragma unroll
  for (int r = 0; r < 4; ++r) {
    float inv = 1.0f / l_r[r];
    size_t row = qrow0 + w * 16 + qd * 4 + r;
#pragma unroll
    for (int td = 0; td < 4; ++td) {
      O[row * DMODEL + hoff + td * 16 + l15] = Oacc[td][r] * inv;
    }
  }
}

// ---------------------------------------------------------------------------
// In-place LayerNorm (over 512) + exact GELU; one block per row.
// ---------------------------------------------------------------------------
__global__ __launch_bounds__(256) void ln_gelu_k(
    float* __restrict__ Y, const float* __restrict__ sc,
    const float* __restrict__ bi) {
  const int t = threadIdx.x;
  float* p = Y + (size_t)blockIdx.x * 512;
  float v0 = p[t], v1 = p[t + 256];
  float s1 = v0 + v1, s2 = v0 * v0 + v1 * v1;
#pragma unroll
  for (int m = 1; m < 64; m <<= 1) {
    s1 += __shfl_xor(s1, m);
    s2 += __shfl_xor(s2, m);
  }
  __shared__ float red[8];
  int w = t >> 6;
  if ((t & 63) == 0) { red[w] = s1; red[4 + w] = s2; }
  __syncthreads();
  s1 = red[0] + red[1] + red[2] + red[3];
  s2 = red[4] + red[5] + red[6] + red[7];
  float mu = s1 * (1.0f / 512.0f);
  float var = s2 * (1.0f / 512.0f) - mu * mu;
  float rstd = rsqrtf(var + 1e-5f);
  float y0 = (v0 - mu) * rstd * sc[t] + bi[t];
  float y1 = (v1 - mu) * rstd * sc[t + 256] + bi[t + 256];
  y0 = 0.5f * y0 * (1.0f + erff(y0 * 0.70710678118654752f));
  y1 = 0.5f * y1 * (1.0f + erff(y1 * 0.70710678118654752f));
  p[t] = y0;
  p[t + 256] = y1;
}

// ---------------------------------------------------------------------------
// Workspace layout (48 MB), stream-order-safe aliasing:
//   [0,4)    qk0b (bf16)      -> later mp0 (fp32, [0,8))
//   [4,8)    qk1b (bf16)
//   [8,12)   vt0 (bf16)       -> later mp1 (fp32, [8,16))
//   [12,16)  vt1 (bf16)
//   [16,24)  m0 (fp32)        -> later y0 (fp32, [16,32))
//   [24,32)  m1 (fp32)
//   [32,48)  y1 (fp32)
// ---------------------------------------------------------------------------
extern "C" void kernel_launch(void* const* d_in, const int* in_sizes, int n_in,
                              void* d_out, int out_size, void* d_ws,
                              size_t ws_size, hipStream_t stream) {
  const float* x0   = (const float*)d_in[0];
  const float* x1   = (const float*)d_in[1];
  const float* Wqk  = (const float*)d_in[2];
  const float* bqk  = (const float*)d_in[3];
  const float* Wv   = (const float*)d_in[4];
  const float* bv   = (const float*)d_in[5];
  const float* Wout = (const float*)d_in[6];
  const float* bout = (const float*)d_in[7];
  const float* W0   = (const float*)d_in[8];
  const float* b0   = (const float*)d_in[9];
  const float* lns  = (const float*)d_in[10];
  const float* lnb  = (const float*)d_in[11];
  const float* W3   = (const float*)d_in[12];
  const float* b3   = (const float*)d_in[13];

  char* ws = (char*)d_ws;
  const size_t MB = 1024 * 1024;
  unsigned short* qk0b = (unsigned short*)(ws + 0 * MB);
  unsigned short* qk1b = (unsigned short*)(ws + 4 * MB);
  unsigned short* vt0  = (unsigned short*)(ws + 8 * MB);
  unsigned short* vt1  = (unsigned short*)(ws + 12 * MB);
  float* m0  = (float*)(ws + 16 * MB);
  float* m1  = (float*)(ws + 24 * MB);
  float* mp0 = (float*)(ws + 0 * MB);   // alias qk0b/qk1b (dead after flash)
  float* mp1 = (float*)(ws + 8 * MB);   // alias vt0/vt1   (dead after flash)
  float* y0  = (float*)(ws + 16 * MB);  // alias m0/m1 (dead after out-proj)
  float* y1  = (float*)(ws + 32 * MB);
  float* out0 = (float*)d_out;
  float* out1 = out0 + (size_t)MROWS * DMODEL;

  dim3 blk(256);
  dim3 g256(MROWS / 64, DMODEL / 64);  // (128, 4)
  dim3 g512(MROWS / 64, 512 / 64);     // (128, 8)
  dim3 ga(SEQ / 64, NH, BATCH);        // (32, 4, 4)

  // Projections: qk -> bf16 natural, v -> bf16 transposed per head
  gemm_k<3><<<g256, blk, 0, stream>>>(x0, nullptr, Wqk, bqk, nullptr, qk0b, MROWS, DMODEL, DMODEL);
  gemm_k<3><<<g256, blk, 0, stream>>>(x1, nullptr, Wqk, bqk, nullptr, qk1b, MROWS, DMODEL, DMODEL);
  gemm_k<4><<<g256, blk, 0, stream>>>(x0, nullptr, Wv, bv, nullptr, vt0, MROWS, DMODEL, DMODEL);
  gemm_k<4><<<g256, blk, 0, stream>>>(x1, nullptr, Wv, bv, nullptr, vt1, MROWS, DMODEL, DMODEL);

  // Bidirectional cross attention (MFMA): m0 = Attn(qk0,qk1,v1); m1 = Attn(qk1,qk0,v0)
  flash_mfma<<<ga, blk, 0, stream>>>(qk0b, qk1b, vt1, m0);
  flash_mfma<<<ga, blk, 0, stream>>>(qk1b, qk0b, vt0, m1);

  // Output projections (fp32)
  gemm_k<0><<<g256, blk, 0, stream>>>(m0, nullptr, Wout, bout, nullptr, mp0, MROWS, DMODEL, DMODEL);
  gemm_k<0><<<g256, blk, 0, stream>>>(m1, nullptr, Wout, bout, nullptr, mp1, MROWS, DMODEL, DMODEL);

  // FFN1: y = concat(x, mproj) @ W0 + b0
  gemm_k<1><<<g512, blk, 0, stream>>>(x0, mp0, W0, b0, nullptr, y0, MROWS, 512, 512);
  gemm_k<1><<<g512, blk, 0, stream>>>(x1, mp1, W0, b0, nullptr, y1, MROWS, 512, 512);

  // LayerNorm + exact GELU, in place
  ln_gelu_k<<<dim3(MROWS), blk, 0, stream>>>(y0, lns, lnb);
  ln_gelu_k<<<dim3(MROWS), blk, 0, stream>>>(y1, lns, lnb);

  // FFN2: out = x + y @ W3 + b3
  gemm_k<2><<<g256, blk, 0, stream>>>(y0, nullptr, W3, b3, x0, out0, MROWS, DMODEL, 512);
  gemm_k<2><<<g256, blk, 0, stream>>>(y1, nullptr, W3, b3, x1, out1, MROWS, DMODEL, 512);
}

// Round 3
// 494.085 us; speedup vs baseline: 2.0674x; 1.1961x over previous
//
#include <hip/hip_runtime.h>
#include <math.h>

#define BATCH 4
#define SEQ 2048
#define DMODEL 256
#define NH 4
#define HD 64
#define MROWS (BATCH * SEQ)  // 8192

typedef short bf16x8 __attribute__((ext_vector_type(8)));
typedef float f32x4 __attribute__((ext_vector_type(4)));

__device__ __forceinline__ unsigned short f2bf(float x) {
  union { float f; unsigned int u; } v;
  v.f = x;
  unsigned int r = (v.u + 0x7FFF + ((v.u >> 16) & 1)) >> 16;
  return (unsigned short)r;
}
__device__ __forceinline__ float bf2f(unsigned short u) {
  union { unsigned int u; float f; } v;
  v.u = ((unsigned int)u) << 16;
  return v.f;
}

// ---------------------------------------------------------------------------
// Cast x0,x1 fp32 -> bf16 (elementwise, float4 vectorized). 4M elems total.
// ---------------------------------------------------------------------------
__global__ __launch_bounds__(256) void cast_x(
    const float* __restrict__ x0, const float* __restrict__ x1,
    unsigned short* __restrict__ x0b, unsigned short* __restrict__ x1b) {
  const int n4 = (MROWS * DMODEL) / 4;  // per tensor
  for (int i = blockIdx.x * 256 + threadIdx.x; i < 2 * n4; i += gridDim.x * 256) {
    const float* src = (i < n4) ? x0 : x1;
    unsigned short* dst = (i < n4) ? x0b : x1b;
    int j = (i < n4) ? i : i - n4;
    float4 v = *(const float4*)&src[j * 4];
    ushort4 o = {f2bf(v.x), f2bf(v.y), f2bf(v.z), f2bf(v.w)};
    *(ushort4*)&dst[j * 4] = o;
  }
}

// ---------------------------------------------------------------------------
// Transpose-cast all 5 weight matrices fp32 [K][N] -> bf16 [N][K] in one
// kernel. Naive per-element (590k elems, L2 absorbs the 2B scatters).
// ---------------------------------------------------------------------------
__global__ __launch_bounds__(256) void cast_w(
    const float* __restrict__ Wqk, const float* __restrict__ Wv,
    const float* __restrict__ Wout, const float* __restrict__ W0,
    const float* __restrict__ W3,
    unsigned short* __restrict__ Wqkt, unsigned short* __restrict__ Wvt,
    unsigned short* __restrict__ Woutt, unsigned short* __restrict__ W0t,
    unsigned short* __restrict__ W3t) {
  int gid = blockIdx.x * 256 + threadIdx.x;  // grid covers 589824
  const float* src; unsigned short* dst; int K, N, idx;
  if (gid < 65536)        { src = Wqk;  dst = Wqkt;  K = 256; N = 256; idx = gid; }
  else if (gid < 131072)  { src = Wv;   dst = Wvt;   K = 256; N = 256; idx = gid - 65536; }
  else if (gid < 196608)  { src = Wout; dst = Woutt; K = 256; N = 256; idx = gid - 131072; }
  else if (gid < 458752)  { src = W0;   dst = W0t;   K = 512; N = 512; idx = gid - 196608; }
  else if (gid < 589824)  { src = W3;   dst = W3t;   K = 512; N = 256; idx = gid - 458752; }
  else return;
  int k = idx / N, n = idx % N;
  dst[n * K + k] = f2bf(src[idx]);
}

// ---------------------------------------------------------------------------
// MFMA bf16 GEMM: C[M,N] = epi(A[M,K] @ W[K,N] + bias), W given transposed
// as Wt[N][K] bf16. Tile 64x64, BK=64, 4 waves, wave w = 16-row band.
// Lane-linear LDS granules (conflict-free b128 on both store and load).
//   MODE 0: bf16 out, natural [M][N]
//   MODE 1: bf16 out transposed per head -> Vt[B][H][HD][SEQ] (N must be 256)
//   MODE 2: A = concat(A, A2) along K (both lda=256); bf16 out
//   MODE 3: fp32 out = resid + A@W + bias
// ---------------------------------------------------------------------------
template <int MODE>
__global__ __launch_bounds__(256) void gemm_bf16(
    const unsigned short* __restrict__ A, const unsigned short* __restrict__ A2,
    const unsigned short* __restrict__ Wt, const float* __restrict__ bias,
    const float* __restrict__ resid, void* __restrict__ Cv, int N, int K) {
  __shared__ unsigned short lds_u[8192];  // 16 KB: A granules [0,4096), B [4096,8192)

  const int t = threadIdx.x;
  const int w = t >> 6, lane = t & 63;
  const int qd = lane >> 4, l15 = lane & 15;
  const int row0 = blockIdx.x * 64;
  const int col0 = blockIdx.y * 64;

  f32x4 acc[4];
#pragma unroll
  for (int tn = 0; tn < 4; ++tn) acc[tn] = (f32x4){0.f, 0.f, 0.f, 0.f};

  for (int k0 = 0; k0 < K; k0 += 64) {
    __syncthreads();  // prior iteration's frag reads complete
    // Staging: 16 wave-tasks (8 A + 8 B), lane-linear stores.
#pragma unroll
    for (int pp = 0; pp < 4; ++pp) {
      int task = pp * 4 + w;
      int isB = task >> 3;
      int tm = (task >> 1) & 3;
      int s = task & 1;
      int colk = k0 + s * 32 + qd * 8;
      uint4 d;
      if (isB) {
        d = *(const uint4*)&Wt[(size_t)(col0 + tm * 16 + l15) * K + colk];
      } else {
        const unsigned short* Ap = A;
        int kk = colk, lda = K;
        if (MODE == 2) {
          Ap = (k0 < 256) ? A : A2;
          kk = colk & 255;
          lda = 256;
        }
        d = *(const uint4*)&Ap[(size_t)(row0 + tm * 16 + l15) * lda + kk];
      }
      *(uint4*)&lds_u[isB * 4096 + ((tm * 2 + s) * 64 + lane) * 8] = d;
    }
    __syncthreads();

    bf16x8 aA0 = *(const bf16x8*)&lds_u[((w * 2 + 0) * 64 + lane) * 8];
    bf16x8 aA1 = *(const bf16x8*)&lds_u[((w * 2 + 1) * 64 + lane) * 8];
#pragma unroll
    for (int tn = 0; tn < 4; ++tn) {
      bf16x8 b0 = *(const bf16x8*)&lds_u[4096 + ((tn * 2 + 0) * 64 + lane) * 8];
      bf16x8 b1 = *(const bf16x8*)&lds_u[4096 + ((tn * 2 + 1) * 64 + lane) * 8];
      acc[tn] = __builtin_amdgcn_mfma_f32_16x16x32_bf16(aA0, b0, acc[tn], 0, 0, 0);
      acc[tn] = __builtin_amdgcn_mfma_f32_16x16x32_bf16(aA1, b1, acc[tn], 0, 0, 0);
    }
  }

  // Epilogue. C-layout: lane holds C[row=w*16+qd*4+r][col=col0+tn*16+l15].
  if (MODE == 1) {
    // Per-head transposed output via LDS transpose (coalesced global writes).
    __syncthreads();
#pragma unroll
    for (int tn = 0; tn < 4; ++tn) {
      int col = col0 + tn * 16 + l15;
      float bb = bias[col];
#pragma unroll
      for (int r = 0; r < 4; ++r) {
        int rloc = w * 16 + qd * 4 + r;
        lds_u[(tn * 16 + l15) * 66 + rloc] = f2bf(acc[tn][r] + bb);
      }
    }
    __syncthreads();
    unsigned short* Vt = (unsigned short*)Cv;
    int b_ = row0 >> 11;
    int h_ = blockIdx.y;  // N==256: 4 head-columns
    int seq0 = row0 & 2047;
    for (int c = t; c < 512; c += 256) {
      int dloc = c >> 3, sc = c & 7;
      uint4 d = *(const uint4*)&lds_u[dloc * 66 + sc * 8];
      *(uint4*)&Vt[((size_t)(b_ * NH + h_) * HD + dloc) * SEQ + seq0 + sc * 8] = d;
    }
    return;
  }

#pragma unroll
  for (int tn = 0; tn < 4; ++tn) {
    int col = col0 + tn * 16 + l15;
    float bb = bias[col];
#pragma unroll
    for (int r = 0; r < 4; ++r) {
      size_t grow = row0 + w * 16 + qd * 4 + r;
      float v = acc[tn][r] + bb;
      if (MODE == 3) {
        float* Co = (float*)Cv;
        Co[grow * N + col] = resid[grow * N + col] + v;
      } else {
        unsigned short* Cb = (unsigned short*)Cv;
        Cb[grow * N + col] = f2bf(v);
      }
    }
  }
}

// ---------------------------------------------------------------------------
// Flash v3: LDS-free, barrier-free, all 16x16x32 MFMA.
// S^T = K.Q (A=K rows m=kv, B=Q rows n=q) with kv row-permutation
//   pi(tk, m) = (tk>>1)*32 + (m>>2)*8 + (tk&1)*4 + (m&3)
// so each lane's 16 P registers form exactly the A-fragment (k=qd*8+j) of
// the P@V MFMAs. All frags are 16B-aligned direct global loads.
// Q,K: bf16 [8192][256]; Vt: bf16 [B][H][64][2048]; O: bf16 [8192][256].
// ---------------------------------------------------------------------------
__global__ __launch_bounds__(256) void flash_v3(
    const unsigned short* __restrict__ Qb, const unsigned short* __restrict__ Kb,
    const unsigned short* __restrict__ Vt, unsigned short* __restrict__ Ob) {
  const int t = threadIdx.x;
  const int w = t >> 6, lane = t & 63;
  const int qd = lane >> 4, l15 = lane & 15;
  const int qt = blockIdx.x, h = blockIdx.y, b = blockIdx.z;
  const size_t qrow0 = (size_t)b * SEQ + (size_t)qt * 64;
  const int hoff = h * HD;
  const unsigned short* vtb = Vt + (size_t)(b * NH + h) * HD * SEQ;
  const float sc2 = 0.125f * 1.44269504f;  // 1/sqrt(64) * log2(e)

  // Q fragments (B-operand): n = w*16+l15 (q), k = s2*32 + qd*8 + j
  bf16x8 qf[2];
#pragma unroll
  for (int s2 = 0; s2 < 2; ++s2)
    qf[s2] = *(const bf16x8*)&Qb[(qrow0 + w * 16 + l15) * DMODEL + hoff + s2 * 32 + qd * 8];

  // Permuted kv row for A-operand loads (m = l15 within tile tk)
  const int kvperm_base = (l15 >> 2) * 8 + (l15 & 3);

  float m_raw = -1e30f, l_run = 0.f;
  f32x4 Oacc[4];
#pragma unroll
  for (int td = 0; td < 4; ++td) Oacc[td] = (f32x4){0.f, 0.f, 0.f, 0.f};

  for (int kt = 0; kt < SEQ / 64; ++kt) {
    const size_t kbase = (size_t)b * SEQ + (size_t)kt * 64;

    // ---- S^T = K.Q (4 kv-tiles of 16) ----
    f32x4 S[4];
#pragma unroll
    for (int tk = 0; tk < 4; ++tk) {
      int kvl = (tk >> 1) * 32 + kvperm_base + (tk & 1) * 4;  // pi(tk, l15)
      bf16x8 kf0 = *(const bf16x8*)&Kb[(kbase + kvl) * DMODEL + hoff + 0 * 32 + qd * 8];
      bf16x8 kf1 = *(const bf16x8*)&Kb[(kbase + kvl) * DMODEL + hoff + 1 * 32 + qd * 8];
      f32x4 a = {0.f, 0.f, 0.f, 0.f};
      a = __builtin_amdgcn_mfma_f32_16x16x32_bf16(kf0, qf[0], a, 0, 0, 0);
      a = __builtin_amdgcn_mfma_f32_16x16x32_bf16(kf1, qf[1], a, 0, 0, 0);
      S[tk] = a;  // lane holds logits[pi(tk, qd*4+r)][q=l15]
    }

    // ---- online softmax over all 16 in-lane values + cross-quad reduce ----
    float mx = S[0][0];
#pragma unroll
    for (int tk = 0; tk < 4; ++tk)
#pragma unroll
      for (int r = 0; r < 4; ++r) mx = fmaxf(mx, S[tk][r]);
    mx = fmaxf(mx, __shfl_xor(mx, 16));
    mx = fmaxf(mx, __shfl_xor(mx, 32));
    float mnew = fmaxf(m_raw, mx);
    float alpha = exp2f((m_raw - mnew) * sc2);
    float ebias = mnew * sc2;
    float p[4][4];
    float rs = 0.f;
#pragma unroll
    for (int tk = 0; tk < 4; ++tk)
#pragma unroll
      for (int r = 0; r < 4; ++r) {
        float pv = exp2f(S[tk][r] * sc2 - ebias);
        p[tk][r] = pv;
        rs += pv;
      }
    rs += __shfl_xor(rs, 16);
    rs += __shfl_xor(rs, 32);
    m_raw = mnew;
    l_run = l_run * alpha + rs;

    // alpha for this lane's O rows (q = qd*4+r) from quad-local lanes
    float aq[4];
#pragma unroll
    for (int r = 0; r < 4; ++r) {
      int src = (qd << 4) + (qd << 2) + r;  // lane with l15 = qd*4+r, same quad
      aq[r] = __shfl(alpha, src, 64);
    }
#pragma unroll
    for (int td = 0; td < 4; ++td)
#pragma unroll
      for (int r = 0; r < 4; ++r) Oacc[td][r] *= aq[r];

    // ---- pack P into A-fragments (k = qd*8 + j, kv = s*32+qd*8+j) ----
    bf16x8 pA[2];
#pragma unroll
    for (int s = 0; s < 2; ++s) {
      bf16x8 v;
#pragma unroll
      for (int j = 0; j < 4; ++j) {
        v[j] = (short)f2bf(p[2 * s][j]);
        v[j + 4] = (short)f2bf(p[2 * s + 1][j]);
      }
      pA[s] = v;
    }

    // ---- O += P @ V ----
#pragma unroll
    for (int td = 0; td < 4; ++td) {
      bf16x8 vf0 = *(const bf16x8*)&vtb[(size_t)(td * 16 + l15) * SEQ + kt * 64 + 0 * 32 + qd * 8];
      bf16x8 vf1 = *(const bf16x8*)&vtb[(size_t)(td * 16 + l15) * SEQ + kt * 64 + 1 * 32 + qd * 8];
      Oacc[td] = __builtin_amdgcn_mfma_f32_16x16x32_bf16(pA[0], vf0, Oacc[td], 0, 0, 0);
      Oacc[td] = __builtin_amdgcn_mfma_f32_16x16x32_bf16(pA[1], vf1, Oacc[td], 0, 0, 0);
    }
  }

  // Epilogue: normalize by l (per q-row) and write bf16 O
  float linv = 1.0f / l_run;
  float lq[4];
#pragma unroll
  for (int r = 0; r < 4; ++r) {
    int src = (qd << 4) + (qd << 2) + r;
    lq[r] = __shfl(linv, src, 64);
  }
#pragma unroll
  for (int r = 0; r < 4; ++r) {
    size_t row = qrow0 + w * 16 + qd * 4 + r;
#pragma unroll
    for (int td = 0; td < 4; ++td)
      Ob[row * DMODEL + hoff + td * 16 + l15] = f2bf(Oacc[td][r] * lq[r]);
  }
}

// ---------------------------------------------------------------------------
// In-place LayerNorm (512) + exact GELU on bf16 rows (fp32 math).
// ---------------------------------------------------------------------------
__global__ __launch_bounds__(256) void ln_gelu_bf16(
    unsigned short* __restrict__ Y, const float* __restrict__ sc,
    const float* __restrict__ bi) {
  const int t = threadIdx.x;
  unsigned short* p = Y + (size_t)blockIdx.x * 512;
  float v0 = bf2f(p[t]), v1 = bf2f(p[t + 256]);
  float s1 = v0 + v1, s2 = v0 * v0 + v1 * v1;
#pragma unroll
  for (int m = 1; m < 64; m <<= 1) {
    s1 += __shfl_xor(s1, m);
    s2 += __shfl_xor(s2, m);
  }
  __shared__ float red[8];
  int w = t >> 6;
  if ((t & 63) == 0) { red[w] = s1; red[4 + w] = s2; }
  __syncthreads();
  s1 = red[0] + red[1] + red[2] + red[3];
  s2 = red[4] + red[5] + red[6] + red[7];
  float mu = s1 * (1.0f / 512.0f);
  float var = s2 * (1.0f / 512.0f) - mu * mu;
  float rstd = rsqrtf(var + 1e-5f);
  float y0 = (v0 - mu) * rstd * sc[t] + bi[t];
  float y1 = (v1 - mu) * rstd * sc[t + 256] + bi[t + 256];
  y0 = 0.5f * y0 * (1.0f + erff(y0 * 0.70710678118654752f));
  y1 = 0.5f * y1 * (1.0f + erff(y1 * 0.70710678118654752f));
  p[t] = f2bf(y0);
  p[t + 256] = f2bf(y1);
}

// ---------------------------------------------------------------------------
// Workspace (MB offsets), stream-order-safe aliasing, total 45 MB:
//   0-8:    x0b, x1b (bf16)
//   8-13:   Wqkt, Wvt, Woutt, W0t, W3t (bf16 transposed, 1MB slots)
//   13-29:  qk0b,qk1b,vt0,vt1 (bf16)  -> later y0b (13-21), y1b (21-29)
//   29-37:  m0b, m1b (bf16)
//   37-45:  mp0b, mp1b (bf16)
// ---------------------------------------------------------------------------
extern "C" void kernel_launch(void* const* d_in, const int* in_sizes, int n_in,
                              void* d_out, int out_size, void* d_ws,
                              size_t ws_size, hipStream_t stream) {
  const float* x0   = (const float*)d_in[0];
  const float* x1   = (const float*)d_in[1];
  const float* Wqk  = (const float*)d_in[2];
  const float* bqk  = (const float*)d_in[3];
  const float* Wv   = (const float*)d_in[4];
  const float* bv   = (const float*)d_in[5];
  const float* Wout = (const float*)d_in[6];
  const float* bout = (const float*)d_in[7];
  const float* W0   = (const float*)d_in[8];
  const float* b0   = (const float*)d_in[9];
  const float* lns  = (const float*)d_in[10];
  const float* lnb  = (const float*)d_in[11];
  const float* W3   = (const float*)d_in[12];
  const float* b3   = (const float*)d_in[13];

  char* ws = (char*)d_ws;
  const size_t MB = 1024 * 1024;
  unsigned short* x0b   = (unsigned short*)(ws + 0 * MB);
  unsigned short* x1b   = (unsigned short*)(ws + 4 * MB);
  unsigned short* Wqkt  = (unsigned short*)(ws + 8 * MB);
  unsigned short* Wvt   = (unsigned short*)(ws + 9 * MB);
  unsigned short* Woutt = (unsigned short*)(ws + 10 * MB);
  unsigned short* W0t   = (unsigned short*)(ws + 11 * MB);
  unsigned short* W3t   = (unsigned short*)(ws + 12 * MB);
  unsigned short* qk0b  = (unsigned short*)(ws + 13 * MB);
  unsigned short* qk1b  = (unsigned short*)(ws + 17 * MB);
  unsigned short* vt0   = (unsigned short*)(ws + 21 * MB);
  unsigned short* vt1   = (unsigned short*)(ws + 25 * MB);
  unsigned short* m0b   = (unsigned short*)(ws + 29 * MB);
  unsigned short* m1b   = (unsigned short*)(ws + 33 * MB);
  unsigned short* mp0b  = (unsigned short*)(ws + 37 * MB);
  unsigned short* mp1b  = (unsigned short*)(ws + 41 * MB);
  unsigned short* y0b   = (unsigned short*)(ws + 13 * MB);  // over qk (dead)
  unsigned short* y1b   = (unsigned short*)(ws + 21 * MB);  // over vt (dead)
  float* out0 = (float*)d_out;
  float* out1 = out0 + (size_t)MROWS * DMODEL;

  dim3 blk(256);
  dim3 g256(MROWS / 64, DMODEL / 64);  // (128, 4)
  dim3 g512(MROWS / 64, 512 / 64);     // (128, 8)
  dim3 ga(SEQ / 64, NH, BATCH);        // (32, 4, 4)

  // Casts
  cast_x<<<dim3(4096), blk, 0, stream>>>(x0, x1, x0b, x1b);
  cast_w<<<dim3(589824 / 256), blk, 0, stream>>>(Wqk, Wv, Wout, W0, W3,
                                                 Wqkt, Wvt, Woutt, W0t, W3t);

  // Projections (MFMA): qk natural bf16, v transposed per head
  gemm_bf16<0><<<g256, blk, 0, stream>>>(x0b, nullptr, Wqkt, bqk, nullptr, qk0b, DMODEL, DMODEL);
  gemm_bf16<0><<<g256, blk, 0, stream>>>(x1b, nullptr, Wqkt, bqk, nullptr, qk1b, DMODEL, DMODEL);
  gemm_bf16<1><<<g256, blk, 0, stream>>>(x0b, nullptr, Wvt, bv, nullptr, vt0, DMODEL, DMODEL);
  gemm_bf16<1><<<g256, blk, 0, stream>>>(x1b, nullptr, Wvt, bv, nullptr, vt1, DMODEL, DMODEL);

  // Bidirectional cross attention
  flash_v3<<<ga, blk, 0, stream>>>(qk0b, qk1b, vt1, m0b);
  flash_v3<<<ga, blk, 0, stream>>>(qk1b, qk0b, vt0, m1b);

  // Output projections
  gemm_bf16<0><<<g256, blk, 0, stream>>>(m0b, nullptr, Woutt, bout, nullptr, mp0b, DMODEL, DMODEL);
  gemm_bf16<0><<<g256, blk, 0, stream>>>(m1b, nullptr, Woutt, bout, nullptr, mp1b, DMODEL, DMODEL);

  // FFN1: y = concat(x, mproj) @ W0 + b0  (bf16 out)
  gemm_bf16<2><<<g512, blk, 0, stream>>>(x0b, mp0b, W0t, b0, nullptr, y0b, 512, 512);
  gemm_bf16<2><<<g512, blk, 0, stream>>>(x1b, mp1b, W0t, b0, nullptr, y1b, 512, 512);

  // LayerNorm + exact GELU in place (bf16)
  ln_gelu_bf16<<<dim3(MROWS), blk, 0, stream>>>(y0b, lns, lnb);
  ln_gelu_bf16<<<dim3(MROWS), blk, 0, stream>>>(y1b, lns, lnb);

  // FFN2: out = x + y @ W3 + b3 (fp32 out, fp32 residual)
  gemm_bf16<3><<<g256, blk, 0, stream>>>(y0b, nullptr, W3t, b3, x0, out0, DMODEL, 512);
  gemm_bf16<3><<<g256, blk, 0, stream>>>(y1b, nullptr, W3t, b3, x1, out1, DMODEL, 512);
}

// Round 4
// 274.788 us; speedup vs baseline: 3.7172x; 1.7981x over previous
//
#include <hip/hip_runtime.h>
#include <math.h>

#define BATCH 4
#define SEQ 2048
#define DMODEL 256
#define NH 4
#define HD 64
#define MROWS (BATCH * SEQ)  // 8192

typedef short bf16x8 __attribute__((ext_vector_type(8)));
typedef float f32x4 __attribute__((ext_vector_type(4)));

__device__ __forceinline__ unsigned short f2bf(float x) {  // RNE
  union { float f; unsigned int u; } v;
  v.f = x;
  unsigned int r = (v.u + 0x7FFF + ((v.u >> 16) & 1)) >> 16;
  return (unsigned short)r;
}
__device__ __forceinline__ unsigned short f2bf_trunc(float x) {  // truncate
  union { float f; unsigned int u; } v;
  v.f = x;
  return (unsigned short)(v.u >> 16);
}
__device__ __forceinline__ float bf2f(unsigned short u) {
  union { unsigned int u; float f; } v;
  v.u = ((unsigned int)u) << 16;
  return v.f;
}

// ---------------------------------------------------------------------------
// Cast x0,x1 fp32 -> bf16.
// ---------------------------------------------------------------------------
__global__ __launch_bounds__(256) void cast_x(
    const float* __restrict__ x0, const float* __restrict__ x1,
    unsigned short* __restrict__ x0b, unsigned short* __restrict__ x1b) {
  const int n4 = (MROWS * DMODEL) / 4;
  for (int i = blockIdx.x * 256 + threadIdx.x; i < 2 * n4; i += gridDim.x * 256) {
    const float* src = (i < n4) ? x0 : x1;
    unsigned short* dst = (i < n4) ? x0b : x1b;
    int j = (i < n4) ? i : i - n4;
    float4 v = *(const float4*)&src[j * 4];
    ushort4 o = {f2bf(v.x), f2bf(v.y), f2bf(v.z), f2bf(v.w)};
    *(ushort4*)&dst[j * 4] = o;
  }
}

// ---------------------------------------------------------------------------
// Transpose-cast all 5 weight matrices fp32 [K][N] -> bf16 [N][K].
// ---------------------------------------------------------------------------
__global__ __launch_bounds__(256) void cast_w(
    const float* __restrict__ Wqk, const float* __restrict__ Wv,
    const float* __restrict__ Wout, const float* __restrict__ W0,
    const float* __restrict__ W3,
    unsigned short* __restrict__ Wqkt, unsigned short* __restrict__ Wvt,
    unsigned short* __restrict__ Woutt, unsigned short* __restrict__ W0t,
    unsigned short* __restrict__ W3t) {
  int gid = blockIdx.x * 256 + threadIdx.x;
  const float* src; unsigned short* dst; int K, N, idx;
  if (gid < 65536)        { src = Wqk;  dst = Wqkt;  K = 256; N = 256; idx = gid; }
  else if (gid < 131072)  { src = Wv;   dst = Wvt;   K = 256; N = 256; idx = gid - 65536; }
  else if (gid < 196608)  { src = Wout; dst = Woutt; K = 256; N = 256; idx = gid - 131072; }
  else if (gid < 458752)  { src = W0;   dst = W0t;   K = 512; N = 512; idx = gid - 196608; }
  else if (gid < 589824)  { src = W3;   dst = W3t;   K = 512; N = 256; idx = gid - 458752; }
  else return;
  int k = idx / N, n = idx % N;
  dst[n * K + k] = f2bf(src[idx]);
}

// ---------------------------------------------------------------------------
// MFMA bf16 GEMM, stream-pair fused (blockIdx.z picks stream 0/1).
// C[M,N] = epi(A[M,K] @ W + bias); W as Wt[N][K] bf16.
// Tile M=128 x N=64, BK=64; 4 waves, wave w = rows [w*32, w*32+32).
// 12 ds_read_b128 per 16 MFMA per wave-iter; lane-linear granules.
//   MODE 0: bf16 out natural
//   MODE 1: bf16 out per-head transposed -> Vt[B][H][HD][SEQ]
//   MODE 2: A = concat(Ax, A2) along K (both lda=256); bf16 out
//   MODE 3: fp32 out = resid + A@W + bias
// ---------------------------------------------------------------------------
template <int MODE>
__global__ __launch_bounds__(256) void gemm2(
    const unsigned short* __restrict__ A_0, const unsigned short* __restrict__ A_1,
    const unsigned short* __restrict__ A2_0, const unsigned short* __restrict__ A2_1,
    const unsigned short* __restrict__ Wt, const float* __restrict__ bias,
    const float* __restrict__ resid_0, const float* __restrict__ resid_1,
    void* __restrict__ C_0, void* __restrict__ C_1, int N, int K) {
  __shared__ unsigned short lds[12288];  // 24 KB: A [0,8192), B [8192,12288)

  const int t = threadIdx.x;
  const int w = t >> 6, lane = t & 63;
  const int qd = lane >> 4, l15 = lane & 15;
  const int row0 = blockIdx.x * 128;
  const int col0 = blockIdx.y * 64;
  const int z = blockIdx.z;
  const unsigned short* A  = z ? A_1 : A_0;
  const unsigned short* A2 = z ? A2_1 : A2_0;
  const float* resid = z ? resid_1 : resid_0;
  void* Cv = z ? C_1 : C_0;

  f32x4 acc[2][4];
#pragma unroll
  for (int mh = 0; mh < 2; ++mh)
#pragma unroll
    for (int tn = 0; tn < 4; ++tn) acc[mh][tn] = (f32x4){0.f, 0.f, 0.f, 0.f};

  for (int k0 = 0; k0 < K; k0 += 64) {
    __syncthreads();
    // 24 staging tasks: 16 A granules + 8 B granules, lane-linear stores.
#pragma unroll
    for (int pp = 0; pp < 6; ++pp) {
      int g = pp * 4 + w;
      uint4 d;
      if (g < 16) {
        int tm = g >> 1, s = g & 1;
        const unsigned short* Ap = A;
        int kk = k0 + s * 32 + qd * 8, lda = K;
        if (MODE == 2) {
          Ap = (k0 < 256) ? A : A2;
          kk = (k0 & 255) + s * 32 + qd * 8;
          lda = 256;
        }
        d = *(const uint4*)&Ap[(size_t)(row0 + tm * 16 + l15) * lda + kk];
        *(uint4*)&lds[(g * 64 + lane) * 8] = d;
      } else {
        int tn = (g - 16) >> 1, s = g & 1;
        d = *(const uint4*)&Wt[(size_t)(col0 + tn * 16 + l15) * K + k0 + s * 32 + qd * 8];
        *(uint4*)&lds[8192 + (((tn * 2 + s) * 64 + lane)) * 8] = d;
      }
    }
    __syncthreads();

    bf16x8 aA[2][2];
#pragma unroll
    for (int mh = 0; mh < 2; ++mh)
#pragma unroll
      for (int s = 0; s < 2; ++s)
        aA[mh][s] = *(const bf16x8*)&lds[((((w * 2 + mh) * 2 + s)) * 64 + lane) * 8];
#pragma unroll
    for (int tn = 0; tn < 4; ++tn) {
      bf16x8 b0 = *(const bf16x8*)&lds[8192 + ((tn * 2 + 0) * 64 + lane) * 8];
      bf16x8 b1 = *(const bf16x8*)&lds[8192 + ((tn * 2 + 1) * 64 + lane) * 8];
#pragma unroll
      for (int mh = 0; mh < 2; ++mh) {
        acc[mh][tn] = __builtin_amdgcn_mfma_f32_16x16x32_bf16(aA[mh][0], b0, acc[mh][tn], 0, 0, 0);
        acc[mh][tn] = __builtin_amdgcn_mfma_f32_16x16x32_bf16(aA[mh][1], b1, acc[mh][tn], 0, 0, 0);
      }
    }
  }

  if (MODE == 1) {
    // Per-head transposed bf16 output via LDS transpose (stride 130 shorts).
    __syncthreads();
#pragma unroll
    for (int tn = 0; tn < 4; ++tn) {
      int col = col0 + tn * 16 + l15;
      float bb = bias[col];
#pragma unroll
      for (int mh = 0; mh < 2; ++mh)
#pragma unroll
        for (int r = 0; r < 4; ++r) {
          int rloc = w * 32 + mh * 16 + qd * 4 + r;
          lds[(tn * 16 + l15) * 130 + rloc] = f2bf(acc[mh][tn][r] + bb);
        }
    }
    __syncthreads();
    unsigned short* Vt = (unsigned short*)Cv;
    int b_ = row0 >> 11;
    int h_ = blockIdx.y;
    int seq0 = row0 & 2047;
    for (int c = t; c < 1024; c += 256) {
      int dloc = c >> 4, sc = c & 15;
      uint4 d = *(const uint4*)&lds[dloc * 130 + sc * 8];
      *(uint4*)&Vt[((size_t)(b_ * NH + h_) * HD + dloc) * SEQ + seq0 + sc * 8] = d;
    }
    return;
  }

#pragma unroll
  for (int tn = 0; tn < 4; ++tn) {
    int col = col0 + tn * 16 + l15;
    float bb = bias[col];
#pragma unroll
    for (int mh = 0; mh < 2; ++mh)
#pragma unroll
      for (int r = 0; r < 4; ++r) {
        size_t grow = row0 + w * 32 + mh * 16 + qd * 4 + r;
        float v = acc[mh][tn][r] + bb;
        if (MODE == 3) {
          ((float*)Cv)[grow * N + col] = resid[grow * N + col] + v;
        } else {
          ((unsigned short*)Cv)[grow * N + col] = f2bf(v);
        }
      }
  }
}

// ---------------------------------------------------------------------------
// flash_v4: register-P MFMA flash attention, LDS-staged K/V, both directions
// fused (blockIdx.z = b*2 + dir). Block = 128 q-rows, wave = 32 q-rows.
// S^T = K.Q with kv row-permutation pi(tk,m) = (tk>>1)*32+(m>>2)*8+(tk&1)*4+(m&3)
// so lane's 16 P values form the A-fragment of the P@V 16x16x32 MFMAs.
// No online max (logits bounded, softmax shift-invariant, fp32 exp2 safe).
// ---------------------------------------------------------------------------
__global__ __launch_bounds__(256) void flash_v4(
    const unsigned short* __restrict__ qk0, const unsigned short* __restrict__ qk1,
    const unsigned short* __restrict__ vt0, const unsigned short* __restrict__ vt1,
    unsigned short* __restrict__ m0, unsigned short* __restrict__ m1) {
  __shared__ unsigned short lds[8192];  // 16 KB: K granules [0,4096), V [4096,8192)

  const int t = threadIdx.x;
  const int w = t >> 6, lane = t & 63;
  const int qd = lane >> 4, l15 = lane & 15;
  const int qt = blockIdx.x, h = blockIdx.y, z = blockIdx.z;
  const int dir = z & 1, b = z >> 1;
  const unsigned short* Qb = dir ? qk1 : qk0;
  const unsigned short* Kb = dir ? qk0 : qk1;
  const unsigned short* Vt = dir ? vt0 : vt1;
  unsigned short* Ob = dir ? m1 : m0;

  const size_t qrow0 = (size_t)b * SEQ + (size_t)qt * 128;
  const int hoff = h * HD;
  const unsigned short* vtb = Vt + (size_t)(b * NH + h) * HD * SEQ;
  const float sc2 = 0.125f * 1.44269504f;  // 1/sqrt(64) * log2(e)

  // Q B-fragments: qf[qh][s]: n = w*32 + qh*16 + l15 (q), k = s*32 + qd*8 + j
  bf16x8 qf[2][2];
#pragma unroll
  for (int qh = 0; qh < 2; ++qh)
#pragma unroll
    for (int s = 0; s < 2; ++s)
      qf[qh][s] = *(const bf16x8*)&Qb[(qrow0 + w * 32 + qh * 16 + l15) * DMODEL + hoff + s * 32 + qd * 8];

  f32x4 Oacc[2][4];
#pragma unroll
  for (int qh = 0; qh < 2; ++qh)
#pragma unroll
    for (int td = 0; td < 4; ++td) Oacc[qh][td] = (f32x4){0.f, 0.f, 0.f, 0.f};
  float l_lane[2] = {0.f, 0.f};

  for (int kt = 0; kt < SEQ / 64; ++kt) {
    const size_t kbase = (size_t)b * SEQ + (size_t)kt * 64;
    __syncthreads();  // prior iteration's frag reads complete
    // Stage 16 granules (8 K perm-rows, 8 V), 4 per wave, lane-linear.
#pragma unroll
    for (int pp = 0; pp < 4; ++pp) {
      int g = pp * 4 + w;
      uint4 d;
      if (g < 8) {
        int tk = g >> 1, s = g & 1;
        int kvl = (tk >> 1) * 32 + (l15 >> 2) * 8 + (tk & 1) * 4 + (l15 & 3);
        d = *(const uint4*)&Kb[(kbase + kvl) * DMODEL + hoff + s * 32 + qd * 8];
      } else {
        int td = (g - 8) >> 1, s = g & 1;
        d = *(const uint4*)&vtb[(size_t)(td * 16 + l15) * SEQ + kt * 64 + s * 32 + qd * 8];
      }
      *(uint4*)&lds[(g * 64 + lane) * 8] = d;
    }
    __syncthreads();

    // Read all K/V fragments once (shared across both q-halves).
    bf16x8 kf[4][2], vf[4][2];
#pragma unroll
    for (int tk = 0; tk < 4; ++tk)
#pragma unroll
      for (int s = 0; s < 2; ++s) {
        kf[tk][s] = *(const bf16x8*)&lds[((tk * 2 + s) * 64 + lane) * 8];
        vf[tk][s] = *(const bf16x8*)&lds[4096 + ((tk * 2 + s) * 64 + lane) * 8];
      }

#pragma unroll
    for (int qh = 0; qh < 2; ++qh) {
      // S^T tiles
      f32x4 S[4];
#pragma unroll
      for (int tk = 0; tk < 4; ++tk) {
        f32x4 a = {0.f, 0.f, 0.f, 0.f};
        a = __builtin_amdgcn_mfma_f32_16x16x32_bf16(kf[tk][0], qf[qh][0], a, 0, 0, 0);
        a = __builtin_amdgcn_mfma_f32_16x16x32_bf16(kf[tk][1], qf[qh][1], a, 0, 0, 0);
        S[tk] = a;  // logits[kv = pi(tk, qd*4+r)][q = l15]
      }
      // softmax numerator (no shift needed: |s*sc2| small, exp2 safe)
      float p[4][4];
      float rs = 0.f;
#pragma unroll
      for (int tk = 0; tk < 4; ++tk)
#pragma unroll
        for (int r = 0; r < 4; ++r) {
          float pv = exp2f(S[tk][r] * sc2);
          p[tk][r] = pv;
          rs += pv;
        }
      l_lane[qh] += rs;
      // pack into A-fragment: kv = s*32 + qd*8 + (tk&1)*4 + r -> j=(tk&1)*4+r
      bf16x8 pA[2];
#pragma unroll
      for (int s = 0; s < 2; ++s) {
        bf16x8 v;
#pragma unroll
        for (int j = 0; j < 4; ++j) {
          v[j] = (short)f2bf_trunc(p[2 * s][j]);
          v[j + 4] = (short)f2bf_trunc(p[2 * s + 1][j]);
        }
        pA[s] = v;
      }
      // O += P @ V
#pragma unroll
      for (int td = 0; td < 4; ++td) {
        Oacc[qh][td] = __builtin_amdgcn_mfma_f32_16x16x32_bf16(pA[0], vf[td][0], Oacc[qh][td], 0, 0, 0);
        Oacc[qh][td] = __builtin_amdgcn_mfma_f32_16x16x32_bf16(pA[1], vf[td][1], Oacc[qh][td], 0, 0, 0);
      }
    }
  }

  // Epilogue: reduce l across qd groups, normalize, write bf16.
#pragma unroll
  for (int qh = 0; qh < 2; ++qh) {
    float l = l_lane[qh];
    l += __shfl_xor(l, 16);
    l += __shfl_xor(l, 32);
    float linv = 1.0f / l;  // valid for q = l15 of this lane
#pragma unroll
    for (int r = 0; r < 4; ++r) {
      float lq = __shfl(linv, qd * 20 + r, 64);  // lane with l15 == qd*4+r
      size_t row = qrow0 + w * 32 + qh * 16 + qd * 4 + r;
#pragma unroll
      for (int td = 0; td < 4; ++td)
        Ob[row * DMODEL + hoff + td * 16 + l15] = f2bf(Oacc[qh][td][r] * lq);
    }
  }
}

// ---------------------------------------------------------------------------
// LayerNorm(512) + exact GELU, both streams in one launch, uint-vectorized.
// ---------------------------------------------------------------------------
__global__ __launch_bounds__(256) void ln_gelu2(
    unsigned short* __restrict__ Y0, unsigned short* __restrict__ Y1,
    const float* __restrict__ sc, const float* __restrict__ bi) {
  const int t = threadIdx.x;
  const int row = blockIdx.x & (MROWS - 1);
  unsigned short* Y = (blockIdx.x >> 13) ? Y1 : Y0;
  unsigned short* p = Y + (size_t)row * 512;
  unsigned int u = *(const unsigned int*)&p[t * 2];
  float v0 = bf2f((unsigned short)(u & 0xFFFF));
  float v1 = bf2f((unsigned short)(u >> 16));
  float s1 = v0 + v1, s2 = v0 * v0 + v1 * v1;
#pragma unroll
  for (int m = 1; m < 64; m <<= 1) {
    s1 += __shfl_xor(s1, m);
    s2 += __shfl_xor(s2, m);
  }
  __shared__ float red[8];
  int w = t >> 6;
  if ((t & 63) == 0) { red[w] = s1; red[4 + w] = s2; }
  __syncthreads();
  s1 = red[0] + red[1] + red[2] + red[3];
  s2 = red[4] + red[5] + red[6] + red[7];
  float mu = s1 * (1.0f / 512.0f);
  float var = s2 * (1.0f / 512.0f) - mu * mu;
  float rstd = rsqrtf(var + 1e-5f);
  float y0 = (v0 - mu) * rstd * sc[t * 2] + bi[t * 2];
  float y1 = (v1 - mu) * rstd * sc[t * 2 + 1] + bi[t * 2 + 1];
  y0 = 0.5f * y0 * (1.0f + erff(y0 * 0.70710678118654752f));
  y1 = 0.5f * y1 * (1.0f + erff(y1 * 0.70710678118654752f));
  unsigned int o = (unsigned int)f2bf(y0) | ((unsigned int)f2bf(y1) << 16);
  *(unsigned int*)&p[t * 2] = o;
}

// ---------------------------------------------------------------------------
// Workspace (MB offsets), total 45 MB, stream-order-safe aliasing:
//   0-8: x0b,x1b | 8-13: Wt's | 13-29: qk0b,qk1b,vt0,vt1 -> y0b(13-21),y1b(21-29)
//   29-37: m0b,m1b | 37-45: mp0b,mp1b
// ---------------------------------------------------------------------------
extern "C" void kernel_launch(void* const* d_in, const int* in_sizes, int n_in,
                              void* d_out, int out_size, void* d_ws,
                              size_t ws_size, hipStream_t stream) {
  const float* x0   = (const float*)d_in[0];
  const float* x1   = (const float*)d_in[1];
  const float* Wqk  = (const float*)d_in[2];
  const float* bqk  = (const float*)d_in[3];
  const float* Wv   = (const float*)d_in[4];
  const float* bv   = (const float*)d_in[5];
  const float* Wout = (const float*)d_in[6];
  const float* bout = (const float*)d_in[7];
  const float* W0   = (const float*)d_in[8];
  const float* b0   = (const float*)d_in[9];
  const float* lns  = (const float*)d_in[10];
  const float* lnb  = (const float*)d_in[11];
  const float* W3   = (const float*)d_in[12];
  const float* b3   = (const float*)d_in[13];

  char* ws = (char*)d_ws;
  const size_t MB = 1024 * 1024;
  unsigned short* x0b   = (unsigned short*)(ws + 0 * MB);
  unsigned short* x1b   = (unsigned short*)(ws + 4 * MB);
  unsigned short* Wqkt  = (unsigned short*)(ws + 8 * MB);
  unsigned short* Wvt   = (unsigned short*)(ws + 9 * MB);
  unsigned short* Woutt = (unsigned short*)(ws + 10 * MB);
  unsigned short* W0t   = (unsigned short*)(ws + 11 * MB);
  unsigned short* W3t   = (unsigned short*)(ws + 12 * MB);
  unsigned short* qk0b  = (unsigned short*)(ws + 13 * MB);
  unsigned short* qk1b  = (unsigned short*)(ws + 17 * MB);
  unsigned short* vt0   = (unsigned short*)(ws + 21 * MB);
  unsigned short* vt1   = (unsigned short*)(ws + 25 * MB);
  unsigned short* m0b   = (unsigned short*)(ws + 29 * MB);
  unsigned short* m1b   = (unsigned short*)(ws + 33 * MB);
  unsigned short* mp0b  = (unsigned short*)(ws + 37 * MB);
  unsigned short* mp1b  = (unsigned short*)(ws + 41 * MB);
  unsigned short* y0b   = (unsigned short*)(ws + 13 * MB);  // over qk (dead)
  unsigned short* y1b   = (unsigned short*)(ws + 21 * MB);  // over vt (dead)
  float* out0 = (float*)d_out;
  float* out1 = out0 + (size_t)MROWS * DMODEL;

  dim3 blk(256);
  dim3 gP(MROWS / 128, 4, 2);    // 64 x 4 x 2 = 512 blocks (N=256)
  dim3 gF1(MROWS / 128, 8, 2);   // N=512
  dim3 gA(SEQ / 128, NH, BATCH * 2);  // 16 x 4 x 8 = 512

  cast_x<<<dim3(4096), blk, 0, stream>>>(x0, x1, x0b, x1b);
  cast_w<<<dim3(589824 / 256), blk, 0, stream>>>(Wqk, Wv, Wout, W0, W3,
                                                 Wqkt, Wvt, Woutt, W0t, W3t);

  // QK projection (both streams), V projection transposed (both streams)
  gemm2<0><<<gP, blk, 0, stream>>>(x0b, x1b, nullptr, nullptr, Wqkt, bqk,
                                   nullptr, nullptr, qk0b, qk1b, DMODEL, DMODEL);
  gemm2<1><<<gP, blk, 0, stream>>>(x0b, x1b, nullptr, nullptr, Wvt, bv,
                                   nullptr, nullptr, vt0, vt1, DMODEL, DMODEL);

  // Bidirectional cross attention, both dirs in one launch
  flash_v4<<<gA, blk, 0, stream>>>(qk0b, qk1b, vt0, vt1, m0b, m1b);

  // Output projection (both streams)
  gemm2<0><<<gP, blk, 0, stream>>>(m0b, m1b, nullptr, nullptr, Woutt, bout,
                                   nullptr, nullptr, mp0b, mp1b, DMODEL, DMODEL);

  // FFN1: y = concat(x, mproj) @ W0 + b0
  gemm2<2><<<gF1, blk, 0, stream>>>(x0b, x1b, mp0b, mp1b, W0t, b0,
                                    nullptr, nullptr, y0b, y1b, 512, 512);

  // LayerNorm + GELU (both streams)
  ln_gelu2<<<dim3(2 * MROWS), blk, 0, stream>>>(y0b, y1b, lns, lnb);

  // FFN2: out = x + y @ W3 + b3 (fp32)
  gemm2<3><<<gP, blk, 0, stream>>>(y0b, y1b, nullptr, nullptr, W3t, b3,
                                   x0, x1, out0, out1, DMODEL, 512);
}

// Round 5
// 268.487 us; speedup vs baseline: 3.8045x; 1.0235x over previous
//
#include <hip/hip_runtime.h>
#include <math.h>

#define BATCH 4
#define SEQ 2048
#define DMODEL 256
#define NH 4
#define HD 64
#define MROWS 8192
#define QKSCALE 0.4246608905f  // sqrt(0.125 * log2(e)); qk scaled by this => QK^T pre-scaled for exp2

typedef short bf16x8 __attribute__((ext_vector_type(8)));
typedef float f32x4 __attribute__((ext_vector_type(4)));
typedef unsigned short us;

__device__ __forceinline__ us f2bf(float x) {  // RNE
  union { float f; unsigned int u; } v;
  v.f = x;
  unsigned int r = (v.u + 0x7FFF + ((v.u >> 16) & 1)) >> 16;
  return (us)r;
}
__device__ __forceinline__ us f2bf_trunc(float x) {
  union { float f; unsigned int u; } v;
  v.f = x;
  return (us)(v.u >> 16);
}
__device__ __forceinline__ float bf2f(us u) {
  union { unsigned int u; float f; } v;
  v.u = ((unsigned int)u) << 16;
  return v.f;
}
// Async global->LDS DMA, 16B/lane. LDS dest must be wave-uniform base; HW
// scatters lane i to base + i*16.
__device__ __forceinline__ void dma16(const void* g, void* l) {
  auto gp = (const __attribute__((address_space(1))) unsigned int*)(unsigned long long)(uintptr_t)g;
  auto lp = (__attribute__((address_space(3))) unsigned int*)(unsigned int)(uintptr_t)l;
  __builtin_amdgcn_global_load_lds(gp, lp, 16, 0, 0);
}

// ---------------------------------------------------------------------------
// Cast x0,x1 fp32 -> bf16.
// ---------------------------------------------------------------------------
__global__ __launch_bounds__(256) void cast_x(
    const float* __restrict__ x0, const float* __restrict__ x1,
    us* __restrict__ x0b, us* __restrict__ x1b) {
  const int n4 = (MROWS * DMODEL) / 4;
  int i = blockIdx.x * 256 + threadIdx.x;
  const float* src = (i < n4) ? x0 : x1;
  us* dst = (i < n4) ? x0b : x1b;
  int j = (i < n4) ? i : i - n4;
  float4 v = *(const float4*)&src[j * 4];
  ushort4 o = {f2bf(v.x), f2bf(v.y), f2bf(v.z), f2bf(v.w)};
  *(ushort4*)&dst[j * 4] = o;
}

// ---------------------------------------------------------------------------
// Weight prep: Wqvt[512][256] = [Wqk | Wv]^T; W1t top half (k<256) = W0_top^T;
// W3t[256][512] = W3^T; fused qv bias.
// ---------------------------------------------------------------------------
__global__ __launch_bounds__(256) void cast_w(
    const float* __restrict__ Wqk, const float* __restrict__ Wv,
    const float* __restrict__ W0, const float* __restrict__ W3,
    const float* __restrict__ bqk, const float* __restrict__ bv,
    us* __restrict__ Wqvt, us* __restrict__ W1t, us* __restrict__ W3t,
    float* __restrict__ bias_qv) {
  int gid = blockIdx.x * 256 + threadIdx.x;
  if (gid < 65536) {
    int k = gid >> 8, j = gid & 255;
    Wqvt[j * 256 + k] = f2bf(Wqk[gid]);
  } else if (gid < 131072) {
    int i = gid - 65536;
    int k = i >> 8, j = i & 255;
    Wqvt[(256 + j) * 256 + k] = f2bf(Wv[i]);
  } else if (gid < 262144) {
    int i = gid - 131072;
    int k = i >> 9, j = i & 511;
    W1t[j * 512 + k] = f2bf(W0[i]);
  } else if (gid < 393216) {
    int i = gid - 262144;
    int k = i >> 8, j = i & 255;
    W3t[j * 512 + k] = f2bf(W3[i]);
  } else if (gid < 393728) {
    int j = gid - 393216;
    bias_qv[j] = (j < 256) ? bqk[j] : bv[j - 256];
  }
}

// ---------------------------------------------------------------------------
// Fold out-proj into FFN1: W1t[j][256+i] = (Wout @ W0_bot)[i][j] (bf16),
// bias1[j] = b0[j] + (bout @ W0_bot)[j]  (fp32). Blocks 0..255: rows of
// Wcomb; block 256: bias.
// ---------------------------------------------------------------------------
__global__ __launch_bounds__(256) void wcomb_k(
    const float* __restrict__ Wout, const float* __restrict__ W0,
    const float* __restrict__ b0, const float* __restrict__ bout,
    us* __restrict__ W1t, float* __restrict__ bias1) {
  int t = threadIdx.x, i = blockIdx.x;
  if (i < 256) {
    float a0 = 0.f, a1 = 0.f;
    for (int k = 0; k < 256; ++k) {
      float wk = Wout[i * 256 + k];
      const float* row = &W0[(256 + k) * 512];
      a0 += wk * row[t];
      a1 += wk * row[t + 256];
    }
    W1t[t * 512 + 256 + i] = f2bf(a0);
    W1t[(t + 256) * 512 + 256 + i] = f2bf(a1);
  } else {
    float a0 = b0[t], a1 = b0[t + 256];
    for (int k = 0; k < 256; ++k) {
      float bk = bout[k];
      const float* row = &W0[(256 + k) * 512];
      a0 += bk * row[t];
      a1 += bk * row[t + 256];
    }
    bias1[t] = a0;
    bias1[t + 256] = a1;
  }
}

// ---------------------------------------------------------------------------
// MFMA bf16 GEMM, 64x64 tile, BK=64, 4 waves (wave = 16-row band), DMA
// staging (global_load_lds x16B), stream-pair fused via blockIdx.z.
//   MODE 0 (QV): coltile<4 -> qk bf16 natural *QKSCALE; coltile>=4 -> Vt
//                per-head transposed [B][H][HD][SEQ]
//   MODE 1 (FFN1): A = concat(Ax, Am) along K (lda=256 each); bf16 out N=512
//   MODE 2 (FFN2): fp32 out = resid + A@W + bias, N=256
// ---------------------------------------------------------------------------
template <int MODE>
__global__ __launch_bounds__(256) void gemm3(
    const us* __restrict__ A0, const us* __restrict__ A1,
    const us* __restrict__ Am0, const us* __restrict__ Am1,
    const us* __restrict__ Wt, const float* __restrict__ bias,
    const float* __restrict__ r0_, const float* __restrict__ r1_,
    void* __restrict__ C0_, void* __restrict__ C1_,
    void* __restrict__ V0_, void* __restrict__ V1_, int K) {
  __shared__ us lds[8192];  // 16 KB = 16 granules x 1 KB
  const int t = threadIdx.x, w = t >> 6, lane = t & 63;
  const int qd = lane >> 4, l15 = lane & 15;
  const int row0 = blockIdx.x * 64;
  const int coltile = blockIdx.y, col0 = coltile * 64;
  const int z = blockIdx.z;
  const us* Ax = z ? A1 : A0;
  const us* Am = z ? Am1 : Am0;

  f32x4 acc[4];
#pragma unroll
  for (int tn = 0; tn < 4; ++tn) acc[tn] = (f32x4){0.f, 0.f, 0.f, 0.f};

  for (int k0 = 0; k0 < K; k0 += 64) {
    __syncthreads();
#pragma unroll
    for (int pp = 0; pp < 4; ++pp) {
      int g = pp * 4 + w;
      const us* src;
      if (g < 8) {
        int tm = g >> 1, s = g & 1;
        const us* Ap = Ax;
        int kk = k0 + s * 32 + qd * 8;
        int lda = K;
        if (MODE == 1) {
          Ap = (k0 < 256) ? Ax : Am;
          kk = kk & 255;
          lda = 256;
        }
        src = &Ap[(size_t)(row0 + tm * 16 + l15) * lda + kk];
      } else {
        int tn = (g - 8) >> 1, s = g & 1;
        src = &Wt[(size_t)(col0 + tn * 16 + l15) * K + k0 + s * 32 + qd * 8];
      }
      dma16(src, &lds[g * 512]);  // wave-uniform LDS base; lane scatters *16B
    }
    __syncthreads();

    bf16x8 aA0 = *(const bf16x8*)&lds[((w * 2 + 0) * 64 + lane) * 8];
    bf16x8 aA1 = *(const bf16x8*)&lds[((w * 2 + 1) * 64 + lane) * 8];
#pragma unroll
    for (int tn = 0; tn < 4; ++tn) {
      bf16x8 b0v = *(const bf16x8*)&lds[((8 + tn * 2 + 0) * 64 + lane) * 8];
      bf16x8 b1v = *(const bf16x8*)&lds[((8 + tn * 2 + 1) * 64 + lane) * 8];
      acc[tn] = __builtin_amdgcn_mfma_f32_16x16x32_bf16(aA0, b0v, acc[tn], 0, 0, 0);
      acc[tn] = __builtin_amdgcn_mfma_f32_16x16x32_bf16(aA1, b1v, acc[tn], 0, 0, 0);
    }
  }

  // C-layout: lane holds C[row0 + w*16 + qd*4 + r][col0 + tn*16 + l15]
  if (MODE == 0) {
    if (coltile < 4) {
      us* C = (us*)(z ? C1_ : C0_);
#pragma unroll
      for (int tn = 0; tn < 4; ++tn) {
        int col = col0 + tn * 16 + l15;
        float bb = bias[col];
#pragma unroll
        for (int r = 0; r < 4; ++r) {
          size_t grow = row0 + w * 16 + qd * 4 + r;
          C[grow * 256 + col] = f2bf((acc[tn][r] + bb) * QKSCALE);
        }
      }
    } else {
      __syncthreads();  // lds reuse for transpose bounce
      int h_ = coltile - 4;
#pragma unroll
      for (int tn = 0; tn < 4; ++tn) {
        int col = col0 + tn * 16 + l15;
        float bb = bias[col];
#pragma unroll
        for (int r = 0; r < 4; ++r) {
          int rloc = w * 16 + qd * 4 + r;
          lds[(tn * 16 + l15) * 66 + rloc] = f2bf(acc[tn][r] + bb);
        }
      }
      __syncthreads();
      us* Vt = (us*)(z ? V1_ : V0_);
      int b_ = row0 >> 11, seq0 = row0 & 2047;
      for (int c = t; c < 512; c += 256) {
        int dloc = c >> 3, scc = c & 7;
        uint4 d = *(const uint4*)&lds[dloc * 66 + scc * 8];
        *(uint4*)&Vt[((size_t)(b_ * NH + h_) * HD + dloc) * SEQ + seq0 + scc * 8] = d;
      }
    }
  } else if (MODE == 1) {
    us* C = (us*)(z ? C1_ : C0_);
#pragma unroll
    for (int tn = 0; tn < 4; ++tn) {
      int col = col0 + tn * 16 + l15;
      float bb = bias[col];
#pragma unroll
      for (int r = 0; r < 4; ++r) {
        size_t grow = row0 + w * 16 + qd * 4 + r;
        C[grow * 512 + col] = f2bf(acc[tn][r] + bb);
      }
    }
  } else {
    float* C = (float*)(z ? C1_ : C0_);
    const float* R = z ? r1_ : r0_;
#pragma unroll
    for (int tn = 0; tn < 4; ++tn) {
      int col = col0 + tn * 16 + l15;
      float bb = bias[col];
#pragma unroll
      for (int r = 0; r < 4; ++r) {
        size_t grow = row0 + w * 16 + qd * 4 + r;
        C[grow * 256 + col] = R[grow * 256 + col] + acc[tn][r] + bb;
      }
    }
  }
}

// ---------------------------------------------------------------------------
// flash_v5: register-P MFMA flash, KV-SPLIT x2 for occupancy (grid 1024 =
// 4 blocks/CU). blockIdx.x = qt + half*16; z = b*2 + dir. Block = 128 q-rows,
// wave = 32 (2 qh). Writes fp32 O-numerator partial + per-row l partial;
// combine_k merges. qk inputs pre-scaled by QKSCALE -> exp2 directly.
// kv row-permutation pi(tk,m) makes lane's 16 P values the A-fragment of
// the P@V MFMAs (no LDS round-trip for P).
// ---------------------------------------------------------------------------
__global__ __launch_bounds__(256) void flash_v5(
    const us* __restrict__ qk0, const us* __restrict__ qk1,
    const us* __restrict__ vt0, const us* __restrict__ vt1,
    float* __restrict__ Opart, float* __restrict__ lpart) {
  __shared__ us lds[8192];  // 16 KB: 8 K granules + 8 V granules
  const int t = threadIdx.x, w = t >> 6, lane = t & 63;
  const int qd = lane >> 4, l15 = lane & 15;
  const int qt = blockIdx.x & 15, half = blockIdx.x >> 4;
  const int h = blockIdx.y, z = blockIdx.z, dir = z & 1, b = z >> 1;
  const us* Qb = dir ? qk1 : qk0;
  const us* Kb = dir ? qk0 : qk1;
  const us* Vt = dir ? vt0 : vt1;
  float* Op = Opart + (size_t)(dir * 2 + half) * (MROWS * DMODEL);
  float* lp = lpart + ((size_t)(dir * 2 + half) * NH + h) * MROWS;
  const size_t qrow0 = (size_t)b * SEQ + (size_t)qt * 128;
  const int hoff = h * HD;
  const us* vtb = Vt + (size_t)(b * NH + h) * HD * SEQ;

  bf16x8 qf[2][2];
#pragma unroll
  for (int qh = 0; qh < 2; ++qh)
#pragma unroll
    for (int s = 0; s < 2; ++s)
      qf[qh][s] = *(const bf16x8*)&Qb[(qrow0 + w * 32 + qh * 16 + l15) * DMODEL + hoff + s * 32 + qd * 8];

  f32x4 Oacc[2][4];
#pragma unroll
  for (int qh = 0; qh < 2; ++qh)
#pragma unroll
    for (int td = 0; td < 4; ++td) Oacc[qh][td] = (f32x4){0.f, 0.f, 0.f, 0.f};
  float l_lane[2] = {0.f, 0.f};

  for (int kt = half * 16; kt < half * 16 + 16; ++kt) {
    const size_t kbase = (size_t)b * SEQ + (size_t)kt * 64;
    __syncthreads();
#pragma unroll
    for (int pp = 0; pp < 4; ++pp) {
      int g = pp * 4 + w;
      const us* src;
      if (g < 8) {
        int tk = g >> 1, s = g & 1;
        int kvl = (tk >> 1) * 32 + (l15 >> 2) * 8 + (tk & 1) * 4 + (l15 & 3);  // pi
        src = &Kb[(kbase + kvl) * DMODEL + hoff + s * 32 + qd * 8];
      } else {
        int td = (g - 8) >> 1, s = g & 1;
        src = &vtb[(size_t)(td * 16 + l15) * SEQ + kt * 64 + s * 32 + qd * 8];
      }
      dma16(src, &lds[g * 512]);
    }
    __syncthreads();

    bf16x8 kf[4][2], vf[4][2];
#pragma unroll
    for (int tk = 0; tk < 4; ++tk)
#pragma unroll
      for (int s = 0; s < 2; ++s) {
        kf[tk][s] = *(const bf16x8*)&lds[((tk * 2 + s) * 64 + lane) * 8];
        vf[tk][s] = *(const bf16x8*)&lds[((8 + tk * 2 + s) * 64 + lane) * 8];
      }

#pragma unroll
    for (int qh = 0; qh < 2; ++qh) {
      f32x4 S[4];
#pragma unroll
      for (int tk = 0; tk < 4; ++tk) {
        f32x4 a = {0.f, 0.f, 0.f, 0.f};
        a = __builtin_amdgcn_mfma_f32_16x16x32_bf16(kf[tk][0], qf[qh][0], a, 0, 0, 0);
        a = __builtin_amdgcn_mfma_f32_16x16x32_bf16(kf[tk][1], qf[qh][1], a, 0, 0, 0);
        S[tk] = a;  // pre-scaled logits[kv = pi(tk, qd*4+r)][q = l15]
      }
      float p[4][4];
      float rs = 0.f;
#pragma unroll
      for (int tk = 0; tk < 4; ++tk)
#pragma unroll
        for (int r = 0; r < 4; ++r) {
          float pv = exp2f(S[tk][r]);
          p[tk][r] = pv;
          rs += pv;
        }
      l_lane[qh] += rs;
      bf16x8 pA[2];
#pragma unroll
      for (int s = 0; s < 2; ++s) {
        bf16x8 v;
#pragma unroll
        for (int j = 0; j < 4; ++j) {
          v[j] = (short)f2bf_trunc(p[2 * s][j]);
          v[j + 4] = (short)f2bf_trunc(p[2 * s + 1][j]);
        }
        pA[s] = v;
      }
#pragma unroll
      for (int td = 0; td < 4; ++td) {
        Oacc[qh][td] = __builtin_amdgcn_mfma_f32_16x16x32_bf16(pA[0], vf[td][0], Oacc[qh][td], 0, 0, 0);
        Oacc[qh][td] = __builtin_amdgcn_mfma_f32_16x16x32_bf16(pA[1], vf[td][1], Oacc[qh][td], 0, 0, 0);
      }
    }
  }

  // Partials out: l (per q-row) and O numerator (fp32, C-layout scatter).
#pragma unroll
  for (int qh = 0; qh < 2; ++qh) {
    float l = l_lane[qh];
    l += __shfl_xor(l, 16);
    l += __shfl_xor(l, 32);
    if (qd == 0) lp[qrow0 + w * 32 + qh * 16 + l15] = l;
#pragma unroll
    for (int r = 0; r < 4; ++r) {
      size_t row = qrow0 + w * 32 + qh * 16 + qd * 4 + r;
#pragma unroll
      for (int td = 0; td < 4; ++td)
        Op[row * DMODEL + hoff + td * 16 + l15] = Oacc[qh][td][r];
    }
  }
}

// ---------------------------------------------------------------------------
// Merge the two kv-halves: m = (Oa + Ob) / (la + lb), bf16 out.
// ---------------------------------------------------------------------------
__global__ __launch_bounds__(256) void combine_k(
    const float* __restrict__ Opart, const float* __restrict__ lpart,
    us* __restrict__ m0b, us* __restrict__ m1b) {
  int gid = blockIdx.x * 256 + threadIdx.x;  // 2 * 8192 * 64
  int dir = gid >= (MROWS * DMODEL / 4);
  int idx = gid - dir * (MROWS * DMODEL / 4);
  int row = idx >> 6;
  int c4 = (idx & 63) << 2;
  int h = c4 >> 6;
  const float* Oa = Opart + (size_t)(dir * 2 + 0) * (MROWS * DMODEL);
  const float* Ob = Opart + (size_t)(dir * 2 + 1) * (MROWS * DMODEL);
  float la = lpart[((size_t)(dir * 2 + 0) * NH + h) * MROWS + row];
  float lb = lpart[((size_t)(dir * 2 + 1) * NH + h) * MROWS + row];
  float inv = 1.0f / (la + lb);
  float4 a = *(const float4*)&Oa[(size_t)row * DMODEL + c4];
  float4 bv = *(const float4*)&Ob[(size_t)row * DMODEL + c4];
  us* m = dir ? m1b : m0b;
  ushort4 o = {f2bf((a.x + bv.x) * inv), f2bf((a.y + bv.y) * inv),
               f2bf((a.z + bv.z) * inv), f2bf((a.w + bv.w) * inv)};
  *(ushort4*)&m[(size_t)row * DMODEL + c4] = o;
}

// ---------------------------------------------------------------------------
// LayerNorm(512) + exact GELU: one WAVE per row (no LDS, no barrier).
// ---------------------------------------------------------------------------
__global__ __launch_bounds__(256) void ln_gelu3(
    us* __restrict__ Y0, us* __restrict__ Y1,
    const float* __restrict__ sc, const float* __restrict__ bi) {
  int w = threadIdx.x >> 6, lane = threadIdx.x & 63;
  int ridx = blockIdx.x * 4 + w;  // 0..16383
  us* Y = (ridx >= MROWS) ? Y1 : Y0;
  int row = ridx & (MROWS - 1);
  us* p = Y + (size_t)row * 512 + lane * 8;
  uint4 u = *(const uint4*)p;
  unsigned int uu[4] = {u.x, u.y, u.z, u.w};
  float v[8];
#pragma unroll
  for (int i = 0; i < 4; ++i) {
    v[2 * i] = bf2f((us)(uu[i] & 0xFFFF));
    v[2 * i + 1] = bf2f((us)(uu[i] >> 16));
  }
  float s1 = 0.f, s2 = 0.f;
#pragma unroll
  for (int i = 0; i < 8; ++i) { s1 += v[i]; s2 += v[i] * v[i]; }
#pragma unroll
  for (int m = 1; m < 64; m <<= 1) {
    s1 += __shfl_xor(s1, m);
    s2 += __shfl_xor(s2, m);
  }
  float mu = s1 * (1.0f / 512.0f);
  float var = s2 * (1.0f / 512.0f) - mu * mu;
  float rstd = rsqrtf(var + 1e-5f);
  int c0 = lane * 8;
  float4 scA = *(const float4*)&sc[c0], scB = *(const float4*)&sc[c0 + 4];
  float4 biA = *(const float4*)&bi[c0], biB = *(const float4*)&bi[c0 + 4];
  float scv[8] = {scA.x, scA.y, scA.z, scA.w, scB.x, scB.y, scB.z, scB.w};
  float biv[8] = {biA.x, biA.y, biA.z, biA.w, biB.x, biB.y, biB.z, biB.w};
  unsigned int ou[4];
#pragma unroll
  for (int i = 0; i < 4; ++i) {
    float y0 = (v[2 * i] - mu) * rstd * scv[2 * i] + biv[2 * i];
    float y1 = (v[2 * i + 1] - mu) * rstd * scv[2 * i + 1] + biv[2 * i + 1];
    y0 = 0.5f * y0 * (1.0f + erff(y0 * 0.70710678118654752f));
    y1 = 0.5f * y1 * (1.0f + erff(y1 * 0.70710678118654752f));
    ou[i] = (unsigned int)f2bf(y0) | ((unsigned int)f2bf(y1) << 16);
  }
  uint4 o = {ou[0], ou[1], ou[2], ou[3]};
  *(uint4*)p = o;
}

// ---------------------------------------------------------------------------
// Workspace (byte offsets), total 67 MB, stream-order-safe aliasing:
//   0/4 MB: x0b,x1b | 8 MB: Wqvt(256K), W1t(512K), W3t(256K) | 9 MB: biases
//   10/14: qk0b,qk1b | 18/22: vt0,vt1 | 26/30: m0b,m1b
//   y0b/y1b overlay 10-26 (qk/vt dead after flash+combine)
//   34-66: Opart[4] fp32 | 66: lpart (1 MB)
// ---------------------------------------------------------------------------
extern "C" void kernel_launch(void* const* d_in, const int* in_sizes, int n_in,
                              void* d_out, int out_size, void* d_ws,
                              size_t ws_size, hipStream_t stream) {
  const float* x0   = (const float*)d_in[0];
  const float* x1   = (const float*)d_in[1];
  const float* Wqk  = (const float*)d_in[2];
  const float* bqk  = (const float*)d_in[3];
  const float* Wv   = (const float*)d_in[4];
  const float* bv   = (const float*)d_in[5];
  const float* Wout = (const float*)d_in[6];
  const float* bout = (const float*)d_in[7];
  const float* W0   = (const float*)d_in[8];
  const float* b0   = (const float*)d_in[9];
  const float* lns  = (const float*)d_in[10];
  const float* lnb  = (const float*)d_in[11];
  const float* W3   = (const float*)d_in[12];
  const float* b3   = (const float*)d_in[13];

  char* ws = (char*)d_ws;
  const size_t MB = 1024 * 1024;
  us* x0b  = (us*)(ws + 0 * MB);
  us* x1b  = (us*)(ws + 4 * MB);
  us* Wqvt = (us*)(ws + 8 * MB);
  us* W1t  = (us*)(ws + 8 * MB + 262144);
  us* W3t  = (us*)(ws + 8 * MB + 786432);
  float* bias_qv = (float*)(ws + 9 * MB);
  float* bias1   = (float*)(ws + 9 * MB + 4096);
  us* qk0b = (us*)(ws + 10 * MB);
  us* qk1b = (us*)(ws + 14 * MB);
  us* vt0  = (us*)(ws + 18 * MB);
  us* vt1  = (us*)(ws + 22 * MB);
  us* m0b  = (us*)(ws + 26 * MB);
  us* m1b  = (us*)(ws + 30 * MB);
  us* y0b  = (us*)(ws + 10 * MB);  // overlay qk (dead after flash)
  us* y1b  = (us*)(ws + 18 * MB);  // overlay vt (dead after combine)
  float* Opart = (float*)(ws + 34 * MB);
  float* lpart = (float*)(ws + 66 * MB);
  float* out0 = (float*)d_out;
  float* out1 = out0 + (size_t)MROWS * DMODEL;

  dim3 blk(256);

  cast_x<<<dim3(4096), blk, 0, stream>>>(x0, x1, x0b, x1b);
  cast_w<<<dim3(1538), blk, 0, stream>>>(Wqk, Wv, W0, W3, bqk, bv,
                                         Wqvt, W1t, W3t, bias_qv);
  wcomb_k<<<dim3(257), blk, 0, stream>>>(Wout, W0, b0, bout, W1t, bias1);

  // QK+V projection fused: N=512 (cols 0-255 qk scaled, 256-511 vt transposed)
  gemm3<0><<<dim3(128, 8, 2), blk, 0, stream>>>(
      x0b, x1b, nullptr, nullptr, Wqvt, bias_qv, nullptr, nullptr,
      qk0b, qk1b, vt0, vt1, 256);

  // Bidirectional cross attention, kv-split x2, both dirs fused
  flash_v5<<<dim3(32, 4, 8), blk, 0, stream>>>(qk0b, qk1b, vt0, vt1, Opart, lpart);
  combine_k<<<dim3(4096), blk, 0, stream>>>(Opart, lpart, m0b, m1b);

  // FFN1 (out-proj algebraically folded): y = concat(x, m) @ [W0top; Wcomb] + bias1
  gemm3<1><<<dim3(128, 8, 2), blk, 0, stream>>>(
      x0b, x1b, m0b, m1b, W1t, bias1, nullptr, nullptr,
      y0b, y1b, nullptr, nullptr, 512);

  ln_gelu3<<<dim3(4096), blk, 0, stream>>>(y0b, y1b, lns, lnb);

  // FFN2: out = x + y @ W3 + b3 (fp32)
  gemm3<2><<<dim3(128, 4, 2), blk, 0, stream>>>(
      y0b, y1b, nullptr, nullptr, W3t, b3, x0, x1,
      out0, out1, nullptr, nullptr, 512);
}

// Round 6
// 229.077 us; speedup vs baseline: 4.4590x; 1.1720x over previous
//
#include <hip/hip_runtime.h>
#include <math.h>

#define BATCH 4
#define SEQ 2048
#define DMODEL 256
#define NH 4
#define HD 64
#define MROWS 8192
#define QKSCALE 0.4246608905f  // sqrt(0.125 * log2(e)): qk pre-scaled => exp2 direct

typedef short bf16x8 __attribute__((ext_vector_type(8)));
typedef float f32x4 __attribute__((ext_vector_type(4)));
typedef unsigned short us;

#if __has_builtin(__builtin_amdgcn_exp2f)
#define EXP2(x) __builtin_amdgcn_exp2f(x)
#else
#define EXP2(x) exp2f(x)
#endif

__device__ __forceinline__ us f2bf(float x) {  // RNE
  union { float f; unsigned int u; } v;
  v.f = x;
  unsigned int r = (v.u + 0x7FFF + ((v.u >> 16) & 1)) >> 16;
  return (us)r;
}
__device__ __forceinline__ float bf2f(us u) {
  union { unsigned int u; float f; } v;
  v.u = ((unsigned int)u) << 16;
  return v.f;
}
__device__ __forceinline__ unsigned int fbits(float x) {
  union { float f; unsigned int u; } v;
  v.f = x;
  return v.u;
}
// v_perm pack: [bf16_trunc(lo) | bf16_trunc(hi)<<16] in one instruction.
__device__ __forceinline__ unsigned int pk2bf(float lo, float hi) {
  return __builtin_amdgcn_perm(fbits(hi), fbits(lo), 0x07060302u);
}
// Async global->LDS DMA, 16B/lane; lane i lands at base + i*16.
__device__ __forceinline__ void dma16(const void* g, void* l) {
  auto gp = (const __attribute__((address_space(1))) unsigned int*)(unsigned long long)(uintptr_t)g;
  auto lp = (__attribute__((address_space(3))) unsigned int*)(unsigned int)(uintptr_t)l;
  __builtin_amdgcn_global_load_lds(gp, lp, 16, 0, 0);
}

// ---------------------------------------------------------------------------
// Cast x0,x1 fp32 -> bf16.
// ---------------------------------------------------------------------------
__global__ __launch_bounds__(256) void cast_x(
    const float* __restrict__ x0, const float* __restrict__ x1,
    us* __restrict__ x0b, us* __restrict__ x1b) {
  const int n4 = (MROWS * DMODEL) / 4;
  int i = blockIdx.x * 256 + threadIdx.x;
  const float* src = (i < n4) ? x0 : x1;
  us* dst = (i < n4) ? x0b : x1b;
  int j = (i < n4) ? i : i - n4;
  float4 v = *(const float4*)&src[j * 4];
  ushort4 o = {f2bf(v.x), f2bf(v.y), f2bf(v.z), f2bf(v.w)};
  *(ushort4*)&dst[j * 4] = o;
}

// ---------------------------------------------------------------------------
// Weight prep: Wqvt[512][256] = [Wqk | Wv]^T; W1t top (k<256) = W0_top^T;
// W3t[256][512] = W3^T; fused qv bias.
// ---------------------------------------------------------------------------
__global__ __launch_bounds__(256) void cast_w(
    const float* __restrict__ Wqk, const float* __restrict__ Wv,
    const float* __restrict__ W0, const float* __restrict__ W3,
    const float* __restrict__ bqk, const float* __restrict__ bv,
    us* __restrict__ Wqvt, us* __restrict__ W1t, us* __restrict__ W3t,
    float* __restrict__ bias_qv) {
  int gid = blockIdx.x * 256 + threadIdx.x;
  if (gid < 65536) {
    int k = gid >> 8, j = gid & 255;
    Wqvt[j * 256 + k] = f2bf(Wqk[gid]);
  } else if (gid < 131072) {
    int i = gid - 65536;
    int k = i >> 8, j = i & 255;
    Wqvt[(256 + j) * 256 + k] = f2bf(Wv[i]);
  } else if (gid < 262144) {
    int i = gid - 131072;
    int k = i >> 9, j = i & 511;
    W1t[j * 512 + k] = f2bf(W0[i]);
  } else if (gid < 393216) {
    int i = gid - 262144;
    int k = i >> 8, j = i & 255;
    W3t[j * 512 + k] = f2bf(W3[i]);
  } else if (gid < 393728) {
    int j = gid - 393216;
    bias_qv[j] = (j < 256) ? bqk[j] : bv[j - 256];
  }
}

// ---------------------------------------------------------------------------
// Fold out-proj into FFN1: W1t[j][256+i] = (Wout @ W0_bot)[i][j] (bf16),
// bias1[j] = b0[j] + (bout @ W0_bot)[j]. 8-way unrolled k-loop (latency).
// ---------------------------------------------------------------------------
__global__ __launch_bounds__(256) void wcomb_k(
    const float* __restrict__ Wout, const float* __restrict__ W0,
    const float* __restrict__ b0, const float* __restrict__ bout,
    us* __restrict__ W1t, float* __restrict__ bias1) {
  int t = threadIdx.x, i = blockIdx.x;
  if (i < 256) {
    float a0 = 0.f, a1 = 0.f;
    for (int k0 = 0; k0 < 256; k0 += 8) {
      float wk[8], r0[8], r1[8];
#pragma unroll
      for (int u = 0; u < 8; ++u) {
        wk[u] = Wout[i * 256 + k0 + u];
        const float* row = &W0[(size_t)(256 + k0 + u) * 512];
        r0[u] = row[t];
        r1[u] = row[t + 256];
      }
#pragma unroll
      for (int u = 0; u < 8; ++u) { a0 += wk[u] * r0[u]; a1 += wk[u] * r1[u]; }
    }
    W1t[t * 512 + 256 + i] = f2bf(a0);
    W1t[(t + 256) * 512 + 256 + i] = f2bf(a1);
  } else {
    float a0 = b0[t], a1 = b0[t + 256];
    for (int k = 0; k < 256; ++k) {
      float bk = bout[k];
      const float* row = &W0[(size_t)(256 + k) * 512];
      a0 += bk * row[t];
      a1 += bk * row[t + 256];
    }
    bias1[t] = a0;
    bias1[t + 256] = a1;
  }
}

// ---------------------------------------------------------------------------
// gemm4: MFMA bf16 GEMM, 128x128 tile, BK=64, 4 waves in 2x2 quadrants
// (wave = 64x64 sub-tile: 8 ds_read_b128 : 16 MFMA per k-half). DMA staging.
// Stream-pair fused via blockIdx.z.
//   MODE 0 (QV, N=512): coltile<2 -> qk bf16 natural *QKSCALE;
//                       coltile>=2 -> Vt per-head transposed [B][H][HD][SEQ]
//   MODE 1 (FFN1, N=512): A = concat(Ax, Am) along K (lda=256 each); bf16 out
//   MODE 2 (FFN2, N=256): fp32 out = resid + A@W + bias
// ---------------------------------------------------------------------------
template <int MODE>
__global__ __launch_bounds__(256) void gemm4(
    const us* __restrict__ A0, const us* __restrict__ A1,
    const us* __restrict__ Am0, const us* __restrict__ Am1,
    const us* __restrict__ Wt, const float* __restrict__ bias,
    const float* __restrict__ r0_, const float* __restrict__ r1_,
    void* __restrict__ C0_, void* __restrict__ C1_,
    void* __restrict__ V0_, void* __restrict__ V1_, int K) {
  __shared__ us lds[17408];  // staging 32KB: A [0,8192), B [8192,16384) shorts

  const int t = threadIdx.x, w = t >> 6, lane = t & 63;
  const int qd = lane >> 4, l15 = lane & 15;
  const int qr = w >> 1, qc = w & 1;
  const int row0 = blockIdx.x * 128;
  const int coltile = blockIdx.y, col0 = coltile * 128;
  const int z = blockIdx.z;
  const us* Ax = z ? A1 : A0;
  const us* Am = z ? Am1 : Am0;

  f32x4 acc[4][4];
#pragma unroll
  for (int i = 0; i < 4; ++i)
#pragma unroll
    for (int j = 0; j < 4; ++j) acc[i][j] = (f32x4){0.f, 0.f, 0.f, 0.f};

  for (int k0 = 0; k0 < K; k0 += 64) {
    __syncthreads();
#pragma unroll
    for (int pp = 0; pp < 8; ++pp) {
      int g = pp * 4 + w;
      const us* src;
      if (g < 16) {  // A granule: tm = g>>1 (16-row band), s = g&1 (k-half)
        int tm = g >> 1, s = g & 1;
        const us* Ap = Ax;
        int kk = k0 + s * 32 + qd * 8;
        int lda = K;
        if (MODE == 1) {
          Ap = (k0 < 256) ? Ax : Am;
          kk = kk & 255;
          lda = 256;
        }
        src = &Ap[(size_t)(row0 + tm * 16 + l15) * lda + kk];
      } else {       // B granule
        int gb = g - 16, tn = gb >> 1, s = gb & 1;
        src = &Wt[(size_t)(col0 + tn * 16 + l15) * K + k0 + s * 32 + qd * 8];
      }
      dma16(src, &lds[g * 512]);
    }
    __syncthreads();

#pragma unroll
    for (int s = 0; s < 2; ++s) {
      bf16x8 af[4], bfr[4];
#pragma unroll
      for (int i = 0; i < 4; ++i) {
        af[i] = *(const bf16x8*)&lds[(((qr * 4 + i) * 2 + s) * 64 + lane) * 8];
        bfr[i] = *(const bf16x8*)&lds[8192 + (((qc * 4 + i) * 2 + s) * 64 + lane) * 8];
      }
#pragma unroll
      for (int i = 0; i < 4; ++i)
#pragma unroll
        for (int j = 0; j < 4; ++j)
          acc[i][j] = __builtin_amdgcn_mfma_f32_16x16x32_bf16(af[i], bfr[j], acc[i][j], 0, 0, 0);
    }
  }

  // C-layout per tile: row = row0 + qr*64 + i*16 + qd*4 + r, col = col0 + qc*64 + j*16 + l15
  if (MODE == 0 && coltile >= 2) {
    // Vt transposed write via LDS bounce. Region per qc: 64 cols x 128 rows,
    // stride 130 (odd dword stride -> conflict-free).
    __syncthreads();
    int base = qc * 8320;
#pragma unroll
    for (int j = 0; j < 4; ++j) {
      int col = col0 + qc * 64 + j * 16 + l15;  // in [256,512)
      float bb = bias[col];
#pragma unroll
      for (int i = 0; i < 4; ++i)
#pragma unroll
        for (int r = 0; r < 4; ++r)
          lds[base + (j * 16 + l15) * 130 + (qr * 64 + i * 16 + qd * 4 + r)] =
              f2bf(acc[i][j][r] + bb);
    }
    __syncthreads();
    us* Vt = (us*)(z ? V1_ : V0_);
    int b_ = row0 >> 11, seq0 = row0 & 2047;
    for (int c = t; c < 2048; c += 256) {
      int hh = c >> 10, cc = c & 1023;
      int dloc = cc >> 4, scc = cc & 15;
      int h = (coltile - 2) * 2 + hh;
      uint4 d = *(const uint4*)&lds[hh * 8320 + dloc * 130 + scc * 8];
      *(uint4*)&Vt[((size_t)(b_ * NH + h) * HD + dloc) * SEQ + seq0 + scc * 8] = d;
    }
    return;
  }

#pragma unroll
  for (int j = 0; j < 4; ++j) {
    int col = col0 + qc * 64 + j * 16 + l15;
    float bb = bias[col];
#pragma unroll
    for (int i = 0; i < 4; ++i)
#pragma unroll
      for (int r = 0; r < 4; ++r) {
        size_t grow = row0 + qr * 64 + i * 16 + qd * 4 + r;
        float v = acc[i][j][r] + bb;
        if (MODE == 0) {
          ((us*)(z ? C1_ : C0_))[grow * 256 + col] = f2bf(v * QKSCALE);
        } else if (MODE == 1) {
          ((us*)(z ? C1_ : C0_))[grow * 512 + col] = f2bf(v);
        } else {
          const float* R = z ? r1_ : r0_;
          ((float*)(z ? C1_ : C0_))[grow * 256 + col] = R[grow * 256 + col] + v;
        }
      }
  }
}

// ---------------------------------------------------------------------------
// flash_v6: register-P MFMA flash, kv-split x2, both dirs fused, LDS
// DOUBLE-BUFFERED DMA prefetch (drain overlaps compute), v_perm P-packing,
// raw v_exp_f32. Block = 128 q-rows, wave = 32. kv row-permutation
// pi(tk,m) = (tk>>1)*32+(m>>2)*8+(tk&1)*4+(m&3) makes lane's 16 P values
// the A-fragment of the P@V MFMAs.
// ---------------------------------------------------------------------------
__global__ __launch_bounds__(256) void flash_v6(
    const us* __restrict__ qk0, const us* __restrict__ qk1,
    const us* __restrict__ vt0, const us* __restrict__ vt1,
    float* __restrict__ Opart, float* __restrict__ lpart) {
  __shared__ us lds[16384];  // 2 x 16KB buffers
  const int t = threadIdx.x, w = t >> 6, lane = t & 63;
  const int qd = lane >> 4, l15 = lane & 15;
  const int qt = blockIdx.x & 15, half = blockIdx.x >> 4;
  const int h = blockIdx.y, z = blockIdx.z, dir = z & 1, b = z >> 1;
  const us* Qb = dir ? qk1 : qk0;
  const us* Kb = dir ? qk0 : qk1;
  const us* Vt = dir ? vt0 : vt1;
  float* Op = Opart + (size_t)(dir * 2 + half) * (MROWS * DMODEL);
  float* lp = lpart + ((size_t)(dir * 2 + half) * NH + h) * MROWS;
  const size_t qrow0 = (size_t)b * SEQ + (size_t)qt * 128;
  const int hoff = h * HD;
  const us* vtb = Vt + (size_t)(b * NH + h) * HD * SEQ;
  const int kt0 = half * 16;

  // Hoisted per-wave DMA source pointers (4 granule tasks per wave).
  const us* sp[4];
  int sstr[4];
#pragma unroll
  for (int pp = 0; pp < 4; ++pp) {
    int g = pp * 4 + w;
    if (g < 8) {
      int tk = g >> 1, s = g & 1;
      int kvl = (tk >> 1) * 32 + (l15 >> 2) * 8 + (tk & 1) * 4 + (l15 & 3);  // pi
      sp[pp] = &Kb[(size_t)(b * SEQ + kt0 * 64 + kvl) * DMODEL + hoff + s * 32 + qd * 8];
      sstr[pp] = 64 * DMODEL;
    } else {
      int td = (g - 8) >> 1, s = g & 1;
      sp[pp] = &vtb[(size_t)(td * 16 + l15) * SEQ + kt0 * 64 + s * 32 + qd * 8];
      sstr[pp] = 64;
    }
  }

  bf16x8 qf[2][2];
#pragma unroll
  for (int qh = 0; qh < 2; ++qh)
#pragma unroll
    for (int s = 0; s < 2; ++s)
      qf[qh][s] = *(const bf16x8*)&Qb[(qrow0 + w * 32 + qh * 16 + l15) * DMODEL + hoff + s * 32 + qd * 8];

  f32x4 Oacc[2][4];
#pragma unroll
  for (int qh = 0; qh < 2; ++qh)
#pragma unroll
    for (int td = 0; td < 4; ++td) Oacc[qh][td] = (f32x4){0.f, 0.f, 0.f, 0.f};
  float l_lane[2] = {0.f, 0.f};

  // Prologue: stage tile kt0 into buffer 0.
#pragma unroll
  for (int pp = 0; pp < 4; ++pp) {
    dma16(sp[pp], &lds[(pp * 4 + w) * 512]);
    sp[pp] += sstr[pp];
  }
  __syncthreads();

  int bsel = 0;
  for (int it = 0; it < 16; ++it) {
    // Prefetch next tile into the other buffer (overlaps this tile's compute;
    // the auto vmcnt(0)-before-barrier drain lands AFTER the compute below).
    if (it < 15) {
#pragma unroll
      for (int pp = 0; pp < 4; ++pp) {
        dma16(sp[pp], &lds[(bsel ^ 1) * 8192 + (pp * 4 + w) * 512]);
        sp[pp] += sstr[pp];
      }
    }
    const us* L = &lds[bsel * 8192];

    bf16x8 kf[4][2], vf[4][2];
#pragma unroll
    for (int tk = 0; tk < 4; ++tk)
#pragma unroll
      for (int s = 0; s < 2; ++s) {
        kf[tk][s] = *(const bf16x8*)&L[((tk * 2 + s) * 64 + lane) * 8];
        vf[tk][s] = *(const bf16x8*)&L[((8 + tk * 2 + s) * 64 + lane) * 8];
      }

#pragma unroll
    for (int qh = 0; qh < 2; ++qh) {
      f32x4 S[4];
#pragma unroll
      for (int tk = 0; tk < 4; ++tk) {
        f32x4 a = {0.f, 0.f, 0.f, 0.f};
        a = __builtin_amdgcn_mfma_f32_16x16x32_bf16(kf[tk][0], qf[qh][0], a, 0, 0, 0);
        a = __builtin_amdgcn_mfma_f32_16x16x32_bf16(kf[tk][1], qf[qh][1], a, 0, 0, 0);
        S[tk] = a;  // pre-scaled logits[kv = pi(tk, qd*4+r)][q = l15]
      }
      float p[4][4];
      float rs = 0.f;
#pragma unroll
      for (int tk = 0; tk < 4; ++tk)
#pragma unroll
        for (int r = 0; r < 4; ++r) {
          float pv = EXP2(S[tk][r]);
          p[tk][r] = pv;
          rs += pv;
        }
      l_lane[qh] += rs;
      // Pack P into A-fragments with v_perm (2 floats -> packed bf16 / instr)
      union { bf16x8 v; unsigned int u[4]; } pk0, pk1;
      pk0.u[0] = pk2bf(p[0][0], p[0][1]);
      pk0.u[1] = pk2bf(p[0][2], p[0][3]);
      pk0.u[2] = pk2bf(p[1][0], p[1][1]);
      pk0.u[3] = pk2bf(p[1][2], p[1][3]);
      pk1.u[0] = pk2bf(p[2][0], p[2][1]);
      pk1.u[1] = pk2bf(p[2][2], p[2][3]);
      pk1.u[2] = pk2bf(p[3][0], p[3][1]);
      pk1.u[3] = pk2bf(p[3][2], p[3][3]);
#pragma unroll
      for (int td = 0; td < 4; ++td) {
        Oacc[qh][td] = __builtin_amdgcn_mfma_f32_16x16x32_bf16(pk0.v, vf[td][0], Oacc[qh][td], 0, 0, 0);
        Oacc[qh][td] = __builtin_amdgcn_mfma_f32_16x16x32_bf16(pk1.v, vf[td][1], Oacc[qh][td], 0, 0, 0);
      }
    }
    __syncthreads();
    bsel ^= 1;
  }

  // Partials: per-row l and fp32 O-numerator (C-layout scatter).
#pragma unroll
  for (int qh = 0; qh < 2; ++qh) {
    float l = l_lane[qh];
    l += __shfl_xor(l, 16);
    l += __shfl_xor(l, 32);
    if (qd == 0) lp[qrow0 + w * 32 + qh * 16 + l15] = l;
#pragma unroll
    for (int r = 0; r < 4; ++r) {
      size_t row = qrow0 + w * 32 + qh * 16 + qd * 4 + r;
#pragma unroll
      for (int td = 0; td < 4; ++td)
        Op[row * DMODEL + hoff + td * 16 + l15] = Oacc[qh][td][r];
    }
  }
}

// ---------------------------------------------------------------------------
// Merge kv-halves: m = (Oa + Ob) / (la + lb), bf16 out.
// ---------------------------------------------------------------------------
__global__ __launch_bounds__(256) void combine_k(
    const float* __restrict__ Opart, const float* __restrict__ lpart,
    us* __restrict__ m0b, us* __restrict__ m1b) {
  int gid = blockIdx.x * 256 + threadIdx.x;
  int dir = gid >= (MROWS * DMODEL / 4);
  int idx = gid - dir * (MROWS * DMODEL / 4);
  int row = idx >> 6;
  int c4 = (idx & 63) << 2;
  int h = c4 >> 6;
  const float* Oa = Opart + (size_t)(dir * 2 + 0) * (MROWS * DMODEL);
  const float* Ob = Opart + (size_t)(dir * 2 + 1) * (MROWS * DMODEL);
  float la = lpart[((size_t)(dir * 2 + 0) * NH + h) * MROWS + row];
  float lb = lpart[((size_t)(dir * 2 + 1) * NH + h) * MROWS + row];
  float inv = 1.0f / (la + lb);
  float4 a = *(const float4*)&Oa[(size_t)row * DMODEL + c4];
  float4 bv = *(const float4*)&Ob[(size_t)row * DMODEL + c4];
  us* m = dir ? m1b : m0b;
  ushort4 o = {f2bf((a.x + bv.x) * inv), f2bf((a.y + bv.y) * inv),
               f2bf((a.z + bv.z) * inv), f2bf((a.w + bv.w) * inv)};
  *(ushort4*)&m[(size_t)row * DMODEL + c4] = o;
}

// ---------------------------------------------------------------------------
// LayerNorm(512) + exact GELU: one wave per row.
// ---------------------------------------------------------------------------
__global__ __launch_bounds__(256) void ln_gelu3(
    us* __restrict__ Y0, us* __restrict__ Y1,
    const float* __restrict__ sc, const float* __restrict__ bi) {
  int w = threadIdx.x >> 6, lane = threadIdx.x & 63;
  int ridx = blockIdx.x * 4 + w;
  us* Y = (ridx >= MROWS) ? Y1 : Y0;
  int row = ridx & (MROWS - 1);
  us* p = Y + (size_t)row * 512 + lane * 8;
  uint4 u = *(const uint4*)p;
  unsigned int uu[4] = {u.x, u.y, u.z, u.w};
  float v[8];
#pragma unroll
  for (int i = 0; i < 4; ++i) {
    v[2 * i] = bf2f((us)(uu[i] & 0xFFFF));
    v[2 * i + 1] = bf2f((us)(uu[i] >> 16));
  }
  float s1 = 0.f, s2 = 0.f;
#pragma unroll
  for (int i = 0; i < 8; ++i) { s1 += v[i]; s2 += v[i] * v[i]; }
#pragma unroll
  for (int m = 1; m < 64; m <<= 1) {
    s1 += __shfl_xor(s1, m);
    s2 += __shfl_xor(s2, m);
  }
  float mu = s1 * (1.0f / 512.0f);
  float var = s2 * (1.0f / 512.0f) - mu * mu;
  float rstd = rsqrtf(var + 1e-5f);
  int c0 = lane * 8;
  float4 scA = *(const float4*)&sc[c0], scB = *(const float4*)&sc[c0 + 4];
  float4 biA = *(const float4*)&bi[c0], biB = *(const float4*)&bi[c0 + 4];
  float scv[8] = {scA.x, scA.y, scA.z, scA.w, scB.x, scB.y, scB.z, scB.w};
  float biv[8] = {biA.x, biA.y, biA.z, biA.w, biB.x, biB.y, biB.z, biB.w};
  unsigned int ou[4];
#pragma unroll
  for (int i = 0; i < 4; ++i) {
    float y0 = (v[2 * i] - mu) * rstd * scv[2 * i] + biv[2 * i];
    float y1 = (v[2 * i + 1] - mu) * rstd * scv[2 * i + 1] + biv[2 * i + 1];
    y0 = 0.5f * y0 * (1.0f + erff(y0 * 0.70710678118654752f));
    y1 = 0.5f * y1 * (1.0f + erff(y1 * 0.70710678118654752f));
    ou[i] = (unsigned int)f2bf(y0) | ((unsigned int)f2bf(y1) << 16);
  }
  uint4 o = {ou[0], ou[1], ou[2], ou[3]};
  *(uint4*)p = o;
}

// ---------------------------------------------------------------------------
// Workspace (byte offsets), total 67 MB, stream-order-safe aliasing:
//   0/4 MB: x0b,x1b | 8 MB: Wqvt, W1t, W3t | 9 MB: biases
//   10/14: qk0b,qk1b | 18/22: vt0,vt1 | 26/30: m0b,m1b
//   y0b/y1b overlay 10-26 | 34-66: Opart[4] fp32 | 66: lpart
// ---------------------------------------------------------------------------
extern "C" void kernel_launch(void* const* d_in, const int* in_sizes, int n_in,
                              void* d_out, int out_size, void* d_ws,
                              size_t ws_size, hipStream_t stream) {
  const float* x0   = (const float*)d_in[0];
  const float* x1   = (const float*)d_in[1];
  const float* Wqk  = (const float*)d_in[2];
  const float* bqk  = (const float*)d_in[3];
  const float* Wv   = (const float*)d_in[4];
  const float* bv   = (const float*)d_in[5];
  const float* Wout = (const float*)d_in[6];
  const float* bout = (const float*)d_in[7];
  const float* W0   = (const float*)d_in[8];
  const float* b0   = (const float*)d_in[9];
  const float* lns  = (const float*)d_in[10];
  const float* lnb  = (const float*)d_in[11];
  const float* W3   = (const float*)d_in[12];
  const float* b3   = (const float*)d_in[13];

  char* ws = (char*)d_ws;
  const size_t MB = 1024 * 1024;
  us* x0b  = (us*)(ws + 0 * MB);
  us* x1b  = (us*)(ws + 4 * MB);
  us* Wqvt = (us*)(ws + 8 * MB);
  us* W1t  = (us*)(ws + 8 * MB + 262144);
  us* W3t  = (us*)(ws + 8 * MB + 786432);
  float* bias_qv = (float*)(ws + 9 * MB);
  float* bias1   = (float*)(ws + 9 * MB + 4096);
  us* qk0b = (us*)(ws + 10 * MB);
  us* qk1b = (us*)(ws + 14 * MB);
  us* vt0  = (us*)(ws + 18 * MB);
  us* vt1  = (us*)(ws + 22 * MB);
  us* m0b  = (us*)(ws + 26 * MB);
  us* m1b  = (us*)(ws + 30 * MB);
  us* y0b  = (us*)(ws + 10 * MB);  // overlay qk (dead after flash)
  us* y1b  = (us*)(ws + 18 * MB);  // overlay vt (dead after combine)
  float* Opart = (float*)(ws + 34 * MB);
  float* lpart = (float*)(ws + 66 * MB);
  float* out0 = (float*)d_out;
  float* out1 = out0 + (size_t)MROWS * DMODEL;

  dim3 blk(256);

  cast_x<<<dim3(4096), blk, 0, stream>>>(x0, x1, x0b, x1b);
  cast_w<<<dim3(1538), blk, 0, stream>>>(Wqk, Wv, W0, W3, bqk, bv,
                                         Wqvt, W1t, W3t, bias_qv);
  wcomb_k<<<dim3(257), blk, 0, stream>>>(Wout, W0, b0, bout, W1t, bias1);

  // QK+V projection fused (N=512): coltile 0-1 qk scaled, 2-3 vt transposed
  gemm4<0><<<dim3(64, 4, 2), blk, 0, stream>>>(
      x0b, x1b, nullptr, nullptr, Wqvt, bias_qv, nullptr, nullptr,
      qk0b, qk1b, vt0, vt1, 256);

  // Bidirectional cross attention, kv-split x2, both dirs fused
  flash_v6<<<dim3(32, 4, 8), blk, 0, stream>>>(qk0b, qk1b, vt0, vt1, Opart, lpart);
  combine_k<<<dim3(4096), blk, 0, stream>>>(Opart, lpart, m0b, m1b);

  // FFN1 (out-proj folded): y = concat(x, m) @ [W0top; Wcomb] + bias1
  gemm4<1><<<dim3(64, 4, 2), blk, 0, stream>>>(
      x0b, x1b, m0b, m1b, W1t, bias1, nullptr, nullptr,
      y0b, y1b, nullptr, nullptr, 512);

  ln_gelu3<<<dim3(4096), blk, 0, stream>>>(y0b, y1b, lns, lnb);

  // FFN2: out = x + y @ W3 + b3 (fp32)
  gemm4<2><<<dim3(64, 2, 2), blk, 0, stream>>>(
      y0b, y1b, nullptr, nullptr, W3t, b3, x0, x1,
      out0, out1, nullptr, nullptr, 512);
}